// Round 12
// baseline (1094.914 us; speedup 1.0000x reference)
//
#include <hip/hip_runtime.h>
#include <hip/hip_bf16.h>
#include <math.h>

#define NN 50000
#define EE 800000
#define BBATCH 64
#define DDIM 64
#define NLAYER 4
#define NIN 7
#define NHEAD 4

typedef __attribute__((ext_vector_type(8))) short short8v;   // 8 bf16 (4 VGPRs)
typedef __attribute__((ext_vector_type(4))) float f32x4;     // mfma acc

// ---------------- device helpers ----------------
static __device__ __forceinline__ float wave_sum(float v) {
#pragma unroll
  for (int m = 32; m > 0; m >>= 1) v += __shfl_xor(v, m, 64);
  return v;
}

static __device__ __forceinline__ float gelu_t(float x) {
  float z = 0.7978845608f * (x + 0.044715f * x * x * x);
  float t = 2.f / (1.f + __expf(-2.f * z)) - 1.f;
  return 0.5f * x * (1.f + t);
}

static __device__ __forceinline__ unsigned short f2b(float v) {
  __hip_bfloat16 b = __float2bfloat16(v);
  return *reinterpret_cast<unsigned short*>(&b);
}

static __device__ __forceinline__ float b2f(unsigned short u) {
  return __builtin_bit_cast(float, (unsigned int)u << 16);
}

// order-preserving float -> uint key (0 is below every real key)
static __device__ __forceinline__ unsigned fkey(float x) {
  unsigned u = __builtin_bit_cast(unsigned, x);
  return (u >> 31) ? ~u : (u | 0x80000000u);
}
static __device__ __forceinline__ float fkey_inv(unsigned k) {
  unsigned u = (k & 0x80000000u) ? (k ^ 0x80000000u) : ~k;
  return __builtin_bit_cast(float, u);
}

// cross-lane add via DPP (VALU pipe, no LDS)
template <int CTRL>
static __device__ __forceinline__ float dppf(float v) {
  int x = __builtin_amdgcn_mov_dpp(__builtin_bit_cast(int, v), CTRL, 0xF, 0xF, true);
  return __builtin_bit_cast(float, x);
}
// quad_perm [1,0,3,2]=0xB1 (xor1), [2,3,0,1]=0x4E (xor2), row_ror:4=0x124, row_ror:8=0x128

static __device__ __forceinline__ void unpack8(uint4 u, float* xs) {
  unsigned int w[4] = {u.x, u.y, u.z, u.w};
#pragma unroll
  for (int k = 0; k < 4; k++) {
    xs[2 * k]     = __builtin_bit_cast(float, w[k] << 16);
    xs[2 * k + 1] = __builtin_bit_cast(float, w[k] & 0xFFFF0000u);
  }
}

static __device__ __forceinline__ short8v pack8(const float* v) {
  short8v r;
#pragma unroll
  for (int j = 0; j < 8; j++) r[j] = (short)f2b(v[j]);
  return r;
}

// ---------------- CSR build ----------------
__global__ void k_count_edges(const int* __restrict__ dst, int e, int* cnt) {
  int i = blockIdx.x * blockDim.x + threadIdx.x;
  if (i < e) atomicAdd(&cnt[dst[i]], 1);
}

// per-1024 chunk sums; +1 per node folds the self loop (cnt zero-initialized)
__global__ void k_scan_bsum(const int* __restrict__ cnt, int n, int* bsum) {
  __shared__ int red[256];
  int b = blockIdx.x, t = threadIdx.x;
  int s = 0;
  for (int i = b * 1024 + t; i < (b + 1) * 1024; i += 256)
    if (i < n) s += cnt[i] + 1;
  red[t] = s;
  __syncthreads();
  for (int o = 128; o > 0; o >>= 1) {
    if (t < o) red[t] += red[t + o];
    __syncthreads();
  }
  if (t == 0) bsum[b] = red[0];
}

__global__ void k_scan_offsets(int* bsum, int nb) {
  if (threadIdx.x == 0 && blockIdx.x == 0) {
    int acc = 0;
    for (int i = 0; i < nb; i++) { int v = bsum[i]; bsum[i] = acc; acc += v; }
  }
}

// scan + self-loop insert fused (nxt aliases cnt); +1 per node folded
__global__ void k_scan_final(int* __restrict__ cnt, int n,
                             const int* __restrict__ bsum, int* __restrict__ indptr,
                             int* __restrict__ esrc) {
  __shared__ int lds[256];
  int b = blockIdx.x, t = threadIdx.x;
  int base = b * 1024;
  int v[4];
  int s = 0;
#pragma unroll
  for (int j = 0; j < 4; j++) {
    int i = base + t * 4 + j;
    v[j] = (i < n) ? cnt[i] + 1 : 0;
    s += v[j];
  }
  lds[t] = s;
  __syncthreads();
  for (int o = 1; o < 256; o <<= 1) {
    int x = (t >= o) ? lds[t - o] : 0;
    __syncthreads();
    lds[t] += x;
    __syncthreads();
  }
  int run = bsum[b] + lds[t] - s;
#pragma unroll
  for (int j = 0; j < 4; j++) {
    int i = base + t * 4 + j;
    if (i < n) {
      indptr[i] = run;
      esrc[run] = i;       // self loop first
      cnt[i] = run + 1;    // cnt becomes nxt
    } else if (i == n) {
      indptr[n] = run;
    }
    run += v[j];
  }
}

__global__ void k_csr_fill(const int* __restrict__ src, const int* __restrict__ dst,
                           int e, int* nxt, int* esrc) {
  int i = blockIdx.x * blockDim.x + threadIdx.x;
  if (i < e) {
    int p = atomicAdd(&nxt[dst[i]], 1);
    esrc[p] = src[i];
  }
}

// ---------------- batch segment starts (batch is sorted) ----------------
__global__ void k_batch_starts(const int* __restrict__ batch, int n, int nb, int* starts) {
  int i = blockIdx.x * blockDim.x + threadIdx.x;
  if (i >= n) return;
  int b = batch[i];
  if (i == 0) {
    for (int x = 0; x <= b; x++) starts[x] = 0;
  } else {
    int pb = batch[i - 1];
    if (pb != b)
      for (int x = pb + 1; x <= b; x++) starts[x] = i;
  }
  if (i == n - 1) {
    for (int x = b + 1; x <= nb; x++) starts[x] = n;
  }
}

// ---------------- merged weight prep ----------------
#define SEG_LR (4 * 512 * 64)
#define SEG_F1 (4 * 128 * 64)
#define SEG_F2 (4 * 64 * 128)
#define SEG_N  (4 * 64 * 64)
#define SEG_D  (64 * 64)
#define WPREP_TOTAL (SEG_LR + SEG_F1 + SEG_F2 + 2 * SEG_N + SEG_D)
__global__ void k_wprep_all(const float* __restrict__ Wl, const float* __restrict__ Wr,
                            const float* __restrict__ F1, const float* __restrict__ F2,
                            const float* __restrict__ N1, const float* __restrict__ N2,
                            const float* __restrict__ D1,
                            unsigned short* __restrict__ wLR, unsigned short* __restrict__ wF1,
                            unsigned short* __restrict__ wF2, unsigned short* __restrict__ wN1,
                            unsigned short* __restrict__ wN2, unsigned short* __restrict__ wD1) {
  int idx = blockIdx.x * blockDim.x + threadIdx.x;
  if (idx < SEG_LR) {
    int l = idx / (512 * 64), rem = idx % (512 * 64);
    int c = rem / 64, k = rem % 64;
    float v = (c < 256) ? Wl[(size_t)l * 64 * 256 + k * 256 + c]
                        : Wr[(size_t)l * 64 * 256 + k * 256 + (c - 256)];
    wLR[idx] = f2b(v);
    return;
  }
  idx -= SEG_LR;
  if (idx < SEG_F1) {
    int l = idx / (128 * 64), rem = idx % (128 * 64);
    int c = rem / 64, k = rem % 64;
    wF1[idx] = f2b(F1[(size_t)l * 64 * 128 + k * 128 + c]);
    return;
  }
  idx -= SEG_F1;
  if (idx < SEG_F2) {
    int l = idx / (64 * 128), rem = idx % (64 * 128);
    int c = rem / 128, k = rem % 128;
    wF2[idx] = f2b(F2[(size_t)l * 128 * 64 + k * 64 + c]);
    return;
  }
  idx -= SEG_F2;
  if (idx < SEG_N) {
    int l = idx / (64 * 64), rem = idx % (64 * 64);
    int c = rem / 64, k = rem % 64;
    wN1[idx] = f2b(N1[(size_t)l * 64 * 64 + k * 64 + c]);
    return;
  }
  idx -= SEG_N;
  if (idx < SEG_N) {
    int l = idx / (64 * 64), rem = idx % (64 * 64);
    int c = rem / 64, k = rem % 64;
    wN2[idx] = f2b(N2[(size_t)l * 64 * 64 + k * 64 + c]);
    return;
  }
  idx -= SEG_N;
  if (idx < SEG_D) {
    int c = idx / 64, k = idx % 64;
    wD1[idx] = f2b(D1[k * 64 + c]);
  }
}

// ---------------- encoder (fp32 h only) ----------------
__global__ void k_encoder(const float* __restrict__ x, const float* __restrict__ W,
                          const float* __restrict__ bias, float* __restrict__ h, int n) {
  int idx = blockIdx.x * blockDim.x + threadIdx.x;
  if (idx >= n * 64) return;
  int i = idx >> 6, d = idx & 63;
  float acc = bias[d];
#pragma unroll
  for (int k = 0; k < NIN; k++) acc += x[i * NIN + k] * W[k * 64 + d];
  h[idx] = acc;
}

// ---------------- xlr GEMM: xlr = (h [+ctx]) @ [Wl|Wr], bf16 out, Co=512 ----------------
template <bool CTX>
__global__ __launch_bounds__(256) void k_xlr(const float* __restrict__ A,
                                             const float* __restrict__ ctxv,
                                             const int* __restrict__ batch,
                                             const unsigned short* __restrict__ Wt,
                                             unsigned short* __restrict__ Cb, int n) {
  const int lane = threadIdx.x & 63, wave = threadIdx.x >> 6;
  const int row0 = blockIdx.x * 64 + wave * 16;
  const int karow = (lane >> 4) * 8;
  const int arow0 = row0 + (lane & 15);
  const int arow = arow0 < n ? arow0 : 0;
  const float* ap = A + (size_t)arow * 64;

  float av[16];
  {
    float4 f0 = *(const float4*)(ap + karow);
    float4 f1 = *(const float4*)(ap + karow + 4);
    float4 f2 = *(const float4*)(ap + 32 + karow);
    float4 f3 = *(const float4*)(ap + 32 + karow + 4);
    av[0] = f0.x; av[1] = f0.y; av[2] = f0.z; av[3] = f0.w;
    av[4] = f1.x; av[5] = f1.y; av[6] = f1.z; av[7] = f1.w;
    av[8] = f2.x; av[9] = f2.y; av[10] = f2.z; av[11] = f2.w;
    av[12] = f3.x; av[13] = f3.y; av[14] = f3.z; av[15] = f3.w;
    if (CTX) {
      const float* cp = ctxv + batch[arow] * 64;
      float4 c0v = *(const float4*)(cp + karow);
      float4 c1v = *(const float4*)(cp + karow + 4);
      float4 c2v = *(const float4*)(cp + 32 + karow);
      float4 c3v = *(const float4*)(cp + 32 + karow + 4);
      av[0] += c0v.x; av[1] += c0v.y; av[2] += c0v.z; av[3] += c0v.w;
      av[4] += c1v.x; av[5] += c1v.y; av[6] += c1v.z; av[7] += c1v.w;
      av[8] += c2v.x; av[9] += c2v.y; av[10] += c2v.z; av[11] += c2v.w;
      av[12] += c3v.x; av[13] += c3v.y; av[14] += c3v.z; av[15] += c3v.w;
    }
  }
  short8v a0 = pack8(av), a1 = pack8(av + 8);

#pragma unroll
  for (int cb = 0; cb < 8; cb++) {
#pragma unroll
    for (int cc = 0; cc < 4; cc++) {
      const int c = cb * 64 + cc * 16 + (lane & 15);
      f32x4 t = {0.f, 0.f, 0.f, 0.f};
      t = __builtin_amdgcn_mfma_f32_16x16x32_bf16(a0, *(const short8v*)(Wt + (size_t)c * 64 + karow), t, 0, 0, 0);
      t = __builtin_amdgcn_mfma_f32_16x16x32_bf16(a1, *(const short8v*)(Wt + (size_t)c * 64 + 32 + karow), t, 0, 0, 0);
#pragma unroll
      for (int r = 0; r < 4; r++) {
        const int row = row0 + (lane >> 4) * 4 + r;
        if (row < n) Cb[(size_t)row * 512 + c] = f2b(t[r]);
      }
    }
  }
}

// ---------------- fused FFN + n2g + pooling + (last block) ctx MLP ----------------
__global__ __launch_bounds__(256) void k_fnp(const unsigned short* __restrict__ A,   // h2b
                                             const unsigned short* __restrict__ F1t, // [128][64]
                                             const float* __restrict__ fb1,
                                             const unsigned short* __restrict__ F2t, // [64][128]
                                             const float* __restrict__ fb2,
                                             float* __restrict__ hOut,
                                             const unsigned short* __restrict__ N1t, // [64][64]
                                             const float* __restrict__ nb1,
                                             const unsigned short* __restrict__ N2t, // [64][64]
                                             const float* __restrict__ nb2,
                                             const int* __restrict__ batch,
                                             float* __restrict__ psum,
                                             unsigned int* __restrict__ pmax,
                                             const float* __restrict__ gW1,
                                             const float* __restrict__ gb1,
                                             const float* __restrict__ gW2,
                                             const float* __restrict__ gb2,
                                             const int* __restrict__ starts,
                                             int* __restrict__ done,
                                             float* __restrict__ ctxOut, int n) {
  __shared__ unsigned short tl[4][16 * 136];  // FFN mid (16x128), reused n2g mid (@72)
  __shared__ unsigned short tn[4][16 * 72];   // n2g input (16x64 @72)
  __shared__ float s_sum[64];
  __shared__ unsigned s_max[64];
  const int lane = threadIdx.x & 63, wave = threadIdx.x >> 6;
  const int row0b = blockIdx.x * 64;
  const int row0 = row0b + wave * 16;
  const int karow = (lane >> 4) * 8;
  const int arow = row0 + (lane & 15);
  const size_t abase = (size_t)(arow < n ? arow : 0) * 64 + karow;
  if (threadIdx.x < 64) { s_sum[threadIdx.x] = 0.f; s_max[threadIdx.x] = 0u; }
  short8v a0 = *(const short8v*)(A + abase);
  short8v a1 = *(const short8v*)(A + abase + 32);

  // ---- FFN stage 1: 64 -> 128, leaky, to tl (stride 136) ----
#pragma unroll
  for (int cc = 0; cc < 8; cc++) {
    const int c = cc * 16 + (lane & 15);
    f32x4 t = {0.f, 0.f, 0.f, 0.f};
    t = __builtin_amdgcn_mfma_f32_16x16x32_bf16(a0, *(const short8v*)(F1t + (size_t)c * 64 + karow), t, 0, 0, 0);
    t = __builtin_amdgcn_mfma_f32_16x16x32_bf16(a1, *(const short8v*)(F1t + (size_t)c * 64 + 32 + karow), t, 0, 0, 0);
    const float bv = fb1[c];
#pragma unroll
    for (int r = 0; r < 4; r++) {
      float v = t[r] + bv;
      v = fmaxf(v, 0.2f * v);
      int rr = (lane >> 4) * 4 + r;
      tl[wave][rr * 136 + c] = f2b(v);
    }
  }

  // ---- FFN stage 2: 128 -> 64, +bias +res(bf16) -> h fp32; bf16 to tn ----
  short8v a2[4];
#pragma unroll
  for (int f = 0; f < 4; f++)
    a2[f] = *(const short8v*)(&tl[wave][(lane & 15) * 136 + f * 32 + karow]);

#pragma unroll
  for (int cc = 0; cc < 4; cc++) {
    const int c = cc * 16 + (lane & 15);
    f32x4 t = {0.f, 0.f, 0.f, 0.f};
#pragma unroll
    for (int f = 0; f < 4; f++)
      t = __builtin_amdgcn_mfma_f32_16x16x32_bf16(a2[f], *(const short8v*)(F2t + (size_t)c * 128 + f * 32 + karow), t, 0, 0, 0);
    const float bv = fb2[c];
#pragma unroll
    for (int r = 0; r < 4; r++) {
      const int row = row0 + (lane >> 4) * 4 + r;
      const int rr = (lane >> 4) * 4 + r;
      float v = t[r] + bv + ((row < n) ? b2f(A[(size_t)row * 64 + c]) : 0.f);
      if (row < n) hOut[(size_t)row * 64 + c] = v;
      tn[wave][rr * 72 + c] = f2b(v);
    }
  }

  // ---- n2g stage 1: 64 -> 64, gelu, to tl (@72) ----
  short8v a3[2];
#pragma unroll
  for (int f = 0; f < 2; f++)
    a3[f] = *(const short8v*)(&tn[wave][(lane & 15) * 72 + f * 32 + karow]);

#pragma unroll
  for (int cc = 0; cc < 4; cc++) {
    const int c = cc * 16 + (lane & 15);
    f32x4 t = {0.f, 0.f, 0.f, 0.f};
    t = __builtin_amdgcn_mfma_f32_16x16x32_bf16(a3[0], *(const short8v*)(N1t + (size_t)c * 64 + karow), t, 0, 0, 0);
    t = __builtin_amdgcn_mfma_f32_16x16x32_bf16(a3[1], *(const short8v*)(N1t + (size_t)c * 64 + 32 + karow), t, 0, 0, 0);
    const float bv = nb1[c];
#pragma unroll
    for (int r = 0; r < 4; r++) {
      int rr = (lane >> 4) * 4 + r;
      tl[wave][rr * 72 + c] = f2b(gelu_t(t[r] + bv));
    }
  }

  // ---- n2g stage 2: 64 -> 64 -> pv ----
  short8v a4[2];
#pragma unroll
  for (int f = 0; f < 2; f++)
    a4[f] = *(const short8v*)(&tl[wave][(lane & 15) * 72 + f * 32 + karow]);

  float pv[4][4];
#pragma unroll
  for (int cc = 0; cc < 4; cc++) {
    const int c = cc * 16 + (lane & 15);
    f32x4 t = {0.f, 0.f, 0.f, 0.f};
    t = __builtin_amdgcn_mfma_f32_16x16x32_bf16(a4[0], *(const short8v*)(N2t + (size_t)c * 64 + karow), t, 0, 0, 0);
    t = __builtin_amdgcn_mfma_f32_16x16x32_bf16(a4[1], *(const short8v*)(N2t + (size_t)c * 64 + 32 + karow), t, 0, 0, 0);
    const float bv = nb2[c];
#pragma unroll
    for (int r = 0; r < 4; r++) pv[cc][r] = t[r] + bv;
  }

  // ---- pooling epilogue ----
  __syncthreads();  // s_sum/s_max init visible
  const int blo = batch[row0b];
  const int last = row0b + 63 < n ? row0b + 63 : n - 1;
  const int bhi = batch[last];
  if (blo == bhi && row0b + 63 < n) {
#pragma unroll
    for (int cc = 0; cc < 4; cc++) {
      const int c = cc * 16 + (lane & 15);
      float s = pv[cc][0] + pv[cc][1] + pv[cc][2] + pv[cc][3];
      float mx = fmaxf(fmaxf(pv[cc][0], pv[cc][1]), fmaxf(pv[cc][2], pv[cc][3]));
      atomicAdd(&s_sum[c], s);
      atomicMax(&s_max[c], fkey(mx));
    }
    __syncthreads();
    if (threadIdx.x < 64) {
      atomicAdd(&psum[blo * 64 + threadIdx.x], s_sum[threadIdx.x]);
      atomicMax(&pmax[blo * 64 + threadIdx.x], s_max[threadIdx.x]);
    }
  } else {
#pragma unroll
    for (int cc = 0; cc < 4; cc++) {
      const int c = cc * 16 + (lane & 15);
#pragma unroll
      for (int r = 0; r < 4; r++) {
        const int row = row0 + (lane >> 4) * 4 + r;
        if (row < n) {
          const int b = batch[row];
          atomicAdd(&psum[b * 64 + c], pv[cc][r]);
          atomicMax(&pmax[b * 64 + c], fkey(pv[cc][r]));
        }
      }
    }
  }

  // ---- last block computes ctx MLP for all batches ----
  __threadfence();
  __shared__ int lastFlag;
  if (threadIdx.x == 0) lastFlag = (atomicAdd(done, 1) == (int)gridDim.x - 1);
  __syncthreads();
  if (!lastFlag) return;
  __threadfence();

  __shared__ float gg[4][128];
  __shared__ float ttw[4][64];
  for (int bb0 = 0; bb0 < BBATCH; bb0 += 4) {
    const int bb = bb0 + wave;
    // coherent reads of pooled values via atomic RMW-identity
    float gm = atomicAdd(&psum[bb * 64 + lane], 0.0f);
    unsigned km = atomicMax(&pmax[bb * 64 + lane], 0u);
    const int cntb = starts[bb + 1] - starts[bb];
    gg[wave][lane] = gm / fmaxf((float)cntb, 1.0f);
    gg[wave][64 + lane] = fkey_inv(km);
    __syncthreads();
    float acc = gb1[lane];
    for (int k = 0; k < 128; k++) acc += gg[wave][k] * gW1[k * 64 + lane];
    ttw[wave][lane] = gelu_t(acc);
    __syncthreads();
    float acc2 = gb2[lane];
    for (int k = 0; k < 64; k++) acc2 += ttw[wave][k] * gW2[k * 64 + lane];
    ctxOut[bb * 64 + lane] = acc2;
  }
}

// ---------------- GATv2 aggregation + residual(+ctx) + LayerNorm ----------------
template <bool CTX>
__global__ __launch_bounds__(256) void k_gat(const unsigned short* __restrict__ xlr,
                                             const float* __restrict__ att,
                                             const float* __restrict__ gbias,
                                             const float* __restrict__ lng,
                                             const float* __restrict__ lnb,
                                             const float* __restrict__ h,
                                             const float* __restrict__ ctxv,
                                             const int* __restrict__ batch,
                                             const int* __restrict__ indptr,
                                             const int* __restrict__ esrc,
                                             unsigned short* __restrict__ h2b, int n) {
  const int wave = threadIdx.x >> 6, lane = threadIdx.x & 63;
  const int node = blockIdx.x * 4 + wave;
  if (node >= n) return;
  const int q = lane >> 4, r = lane & 15;
  const int c = r & 3;
  const int doff = (r >> 2) * 64 + c * 16;

  float xr_d[16], att_d[16];
  {
    const uint4* xp = (const uint4*)(xlr + (size_t)node * 512 + 256 + doff);
    uint4 u0 = xp[0], u1 = xp[1];
    unpack8(u0, xr_d);
    unpack8(u1, xr_d + 8);
    const float4* ap = (const float4*)(att + doff);
#pragma unroll
    for (int k = 0; k < 4; k++) {
      float4 a = ap[k];
      att_d[4 * k] = a.x; att_d[4 * k + 1] = a.y;
      att_d[4 * k + 2] = a.z; att_d[4 * k + 3] = a.w;
    }
  }

  float acc[16] = {};
  float den = 0.f;
  const int beg = indptr[node], end = indptr[node + 1];

  // 2-deep pipeline: data 1 ahead, esrc index 2 ahead
  int j0 = beg + q;
  int s_cur = esrc[(j0 < end) ? j0 : beg];
  const uint4* xp0 = (const uint4*)(xlr + (size_t)s_cur * 512 + doff);
  uint4 u0 = xp0[0], u1 = xp0[1];
  int jn1 = beg + 4 + q;
  int s_nxt = esrc[(jn1 < end && beg + 4 < end) ? jn1 : beg];

  for (int jb = beg; jb < end; jb += 4) {
    const uint4 cu0 = u0, cu1 = u1;
    const bool cvalid = (jb + q) < end;
    if (jb + 4 < end) {
      const uint4* xpn = (const uint4*)(xlr + (size_t)s_nxt * 512 + doff);
      u0 = xpn[0];
      u1 = xpn[1];
      if (jb + 8 < end) {
        const int jn = jb + 8 + q;
        s_nxt = esrc[(jn < end) ? jn : beg];
      }
    }
    float xs[16];
    unpack8(cu0, xs);
    unpack8(cu1, xs + 8);
    float p0 = 0.f, p1 = 0.f, p2 = 0.f, p3 = 0.f;
#pragma unroll
    for (int k = 0; k < 4; k++) {
      float t0 = xs[4 * k + 0] + xr_d[4 * k + 0]; t0 = fmaxf(t0, 0.2f * t0); p0 = fmaf(t0, att_d[4 * k + 0], p0);
      float t1 = xs[4 * k + 1] + xr_d[4 * k + 1]; t1 = fmaxf(t1, 0.2f * t1); p1 = fmaf(t1, att_d[4 * k + 1], p1);
      float t2 = xs[4 * k + 2] + xr_d[4 * k + 2]; t2 = fmaxf(t2, 0.2f * t2); p2 = fmaf(t2, att_d[4 * k + 2], p2);
      float t3 = xs[4 * k + 3] + xr_d[4 * k + 3]; t3 = fmaxf(t3, 0.2f * t3); p3 = fmaf(t3, att_d[4 * k + 3], p3);
    }
    float p = (p0 + p1) + (p2 + p3);
    p += dppf<0xB1>(p);
    p += dppf<0x4E>(p);
    const float pw = cvalid ? __expf(fminf(p, 60.f)) : 0.f;
    den += pw;
#pragma unroll
    for (int d = 0; d < 16; d++) acc[d] = fmaf(pw, xs[d], acc[d]);
  }

  den += __shfl_xor(den, 16, 64);
  den += __shfl_xor(den, 32, 64);
#pragma unroll
  for (int d = 0; d < 16; d++) {
    acc[d] += __shfl_xor(acc[d], 16, 64);
    acc[d] += __shfl_xor(acc[d], 32, 64);
  }

  const float rden = 0.25f / (den + 1e-16f);
  float y[16];
  float s4 = 0.f;
  const float4* hp = (const float4*)(h + (size_t)node * 64 + c * 16);
  const float4* gp = (const float4*)(gbias + c * 16);
  const float4* cp = CTX ? (const float4*)(ctxv + batch[node] * 64 + c * 16) : nullptr;
#pragma unroll
  for (int k = 0; k < 4; k++) {
    float4 hv = hp[k], gv = gp[k];
    if (CTX) {
      float4 cv = cp[k];
      hv.x += cv.x; hv.y += cv.y; hv.z += cv.z; hv.w += cv.w;
    }
    float hf[4] = {hv.x, hv.y, hv.z, hv.w};
    float gf[4] = {gv.x, gv.y, gv.z, gv.w};
#pragma unroll
    for (int d2 = 0; d2 < 4; d2++) {
      int d = 4 * k + d2;
      float v = acc[d] * rden;
      v += dppf<0x124>(v);
      v += dppf<0x128>(v);
      y[d] = hf[d2] + v + gf[d2];
      s4 += y[d];
    }
  }

  const float mu = wave_sum(s4) * (1.f / 1024.f);
  float v4 = 0.f;
  float dv[16];
#pragma unroll
  for (int d = 0; d < 16; d++) {
    dv[d] = y[d] - mu;
    v4 += dv[d] * dv[d];
  }
  const float var = wave_sum(v4) * (1.f / 1024.f);
  const float rstd = rsqrtf(var + 1e-5f);

  if (lane < 4) {
    uint2* outb = (uint2*)(h2b + (size_t)node * 64 + lane * 16);
    const float4* lgp = (const float4*)(lng + lane * 16);
    const float4* lbp = (const float4*)(lnb + lane * 16);
#pragma unroll
    for (int k = 0; k < 4; k++) {
      float4 g = lgp[k], b = lbp[k];
      float o0 = dv[4 * k + 0] * rstd * g.x + b.x;
      float o1 = dv[4 * k + 1] * rstd * g.y + b.y;
      float o2 = dv[4 * k + 2] * rstd * g.z + b.z;
      float o3 = dv[4 * k + 3] * rstd * g.w + b.w;
      uint2 pk;
      pk.x = (unsigned int)f2b(o0) | ((unsigned int)f2b(o1) << 16);
      pk.y = (unsigned int)f2b(o2) | ((unsigned int)f2b(o3) << 16);
      outb[k] = pk;
    }
  }
}

// ---------------- fused decoder: out = gelu((h+ctx)@W1+b1)@W2 + b2 ----------------
__global__ __launch_bounds__(256) void k_dec(const float* __restrict__ A,            // h fp32
                                             const float* __restrict__ ctxv,
                                             const int* __restrict__ batch,
                                             const unsigned short* __restrict__ W1t,
                                             const float* __restrict__ b1,
                                             const float* __restrict__ W2,
                                             const float* __restrict__ b2,
                                             float* __restrict__ out, int n) {
  const int lane = threadIdx.x & 63, wave = threadIdx.x >> 6;
  const int row0 = blockIdx.x * 64 + wave * 16;
  const int karow = (lane >> 4) * 8;
  const int arow0 = row0 + (lane & 15);
  const int arow = arow0 < n ? arow0 : 0;
  const float* ap = A + (size_t)arow * 64;
  const float* cp = ctxv + batch[arow] * 64;

  float av[16];
  {
    float4 f0 = *(const float4*)(ap + karow);
    float4 f1 = *(const float4*)(ap + karow + 4);
    float4 f2 = *(const float4*)(ap + 32 + karow);
    float4 f3 = *(const float4*)(ap + 32 + karow + 4);
    float4 c0v = *(const float4*)(cp + karow);
    float4 c1v = *(const float4*)(cp + karow + 4);
    float4 c2v = *(const float4*)(cp + 32 + karow);
    float4 c3v = *(const float4*)(cp + 32 + karow + 4);
    av[0] = f0.x + c0v.x; av[1] = f0.y + c0v.y; av[2] = f0.z + c0v.z; av[3] = f0.w + c0v.w;
    av[4] = f1.x + c1v.x; av[5] = f1.y + c1v.y; av[6] = f1.z + c1v.z; av[7] = f1.w + c1v.w;
    av[8] = f2.x + c2v.x; av[9] = f2.y + c2v.y; av[10] = f2.z + c2v.z; av[11] = f2.w + c2v.w;
    av[12] = f3.x + c3v.x; av[13] = f3.y + c3v.y; av[14] = f3.z + c3v.z; av[15] = f3.w + c3v.w;
  }
  short8v a0 = pack8(av), a1 = pack8(av + 8);

  float o0[4] = {}, o1[4] = {};
#pragma unroll
  for (int cc = 0; cc < 4; cc++) {
    const int cidx = cc * 16 + (lane & 15);
    f32x4 t = {0.f, 0.f, 0.f, 0.f};
    t = __builtin_amdgcn_mfma_f32_16x16x32_bf16(a0, *(const short8v*)(W1t + (size_t)cidx * 64 + karow), t, 0, 0, 0);
    t = __builtin_amdgcn_mfma_f32_16x16x32_bf16(a1, *(const short8v*)(W1t + (size_t)cidx * 64 + 32 + karow), t, 0, 0, 0);
    const float bv = b1[cidx];
    const float w0 = W2[cidx * 2 + 0], w1 = W2[cidx * 2 + 1];
#pragma unroll
    for (int r = 0; r < 4; r++) {
      float v = gelu_t(t[r] + bv);
      o0[r] = fmaf(v, w0, o0[r]);
      o1[r] = fmaf(v, w1, o1[r]);
    }
  }
#pragma unroll
  for (int m = 1; m < 16; m <<= 1) {
#pragma unroll
    for (int r = 0; r < 4; r++) {
      o0[r] += __shfl_xor(o0[r], m, 64);
      o1[r] += __shfl_xor(o1[r], m, 64);
    }
  }
  if ((lane & 15) == 0) {
#pragma unroll
    for (int r = 0; r < 4; r++) {
      const int row = row0 + (lane >> 4) * 4 + r;
      if (row < n) {
        out[2 * row] = o0[r] + b2[0];
        out[2 * row + 1] = o1[r] + b2[1];
      }
    }
  }
}

// ---------------- host ----------------
extern "C" void kernel_launch(void* const* d_in, const int* in_sizes, int n_in,
                              void* d_out, int out_size, void* d_ws, size_t ws_size,
                              hipStream_t stream) {
  const float* x = (const float*)d_in[0];
  const int* ei = (const int*)d_in[1];
  const int* batch = (const int*)d_in[2];
  const float* enc_W = (const float*)d_in[3];
  const float* enc_b = (const float*)d_in[4];
  const float* gat_Wl = (const float*)d_in[5];
  const float* gat_Wr = (const float*)d_in[6];
  const float* gat_att = (const float*)d_in[7];
  const float* gat_b = (const float*)d_in[8];
  const float* ln_g = (const float*)d_in[9];
  const float* ln_b = (const float*)d_in[10];
  const float* ffn_W1 = (const float*)d_in[11];
  const float* ffn_b1 = (const float*)d_in[12];
  const float* ffn_W2 = (const float*)d_in[13];
  const float* ffn_b2 = (const float*)d_in[14];
  const float* n2g_W1 = (const float*)d_in[15];
  const float* n2g_b1 = (const float*)d_in[16];
  const float* n2g_W2 = (const float*)d_in[17];
  const float* n2g_b2 = (const float*)d_in[18];
  const float* g2n_W1 = (const float*)d_in[19];
  const float* g2n_b1 = (const float*)d_in[20];
  const float* g2n_W2 = (const float*)d_in[21];
  const float* g2n_b2 = (const float*)d_in[22];
  const float* dec_W1 = (const float*)d_in[23];
  const float* dec_b1 = (const float*)d_in[24];
  const float* dec_W2 = (const float*)d_in[25];
  const float* dec_b2 = (const float*)d_in[26];

  const int N = NN, E = EE;
  const int* e_src = ei;
  const int* e_dst = ei + E;

  // ---- workspace carve ----
  // [psum_all | pmax_all | done(4) | cnt] contiguous -> one upfront memset.
  float* h = (float*)d_ws;                    // N*64
  float* ctx = h + (size_t)N * 64;            // B*64
  float* psum_all = ctx + BBATCH * 64;        // 4 * B*64
  unsigned int* pmax_all = (unsigned int*)(psum_all + 4 * BBATCH * 64);  // 4 * B*64
  int* done = (int*)(pmax_all + 4 * BBATCH * 64);  // 4
  int* cnt = done + 4;                        // N (zero-init; becomes nxt)
  int* indptr = cnt + N;                      // N+1
  int* esrc = indptr + N + 1;                 // E+N
  int* bsum = esrc + (E + N);                 // 64
  int* starts = bsum + 64;                    // B+1
  size_t off = (size_t)(starts + BBATCH + 1) - (size_t)d_ws;
  off = (off + 15) & ~(size_t)15;
  unsigned short* h2b = (unsigned short*)((char*)d_ws + off);  // N*64
  unsigned short* xlr = h2b + (size_t)N * 64;                  // N*512 (xl | xr)
  unsigned short* wLR = xlr + (size_t)N * 512;                 // 4*512*64
  unsigned short* wF1 = wLR + SEG_LR;
  unsigned short* wF2 = wF1 + SEG_F1;
  unsigned short* wN1 = wF2 + SEG_F2;
  unsigned short* wN2 = wN1 + SEG_N;
  unsigned short* wD1 = wN2 + SEG_N;

  const int TPB = 256;
  const int NBLK_SCAN = (N + 1 + 1023) / 1024;

  // ---- zero psum/pmax/done/cnt in one memset ----
  hipMemsetAsync(psum_all, 0,
                 (size_t)4 * BBATCH * 64 * (sizeof(float) + sizeof(unsigned int)) +
                 4 * sizeof(int) + (size_t)N * sizeof(int),
                 stream);

  // ---- weight prep (one dispatch) ----
  hipLaunchKernelGGL(k_wprep_all, dim3((WPREP_TOTAL + 255) / 256), dim3(256), 0, stream,
                     gat_Wl, gat_Wr, ffn_W1, ffn_W2, n2g_W1, n2g_W2, dec_W1,
                     wLR, wF1, wF2, wN1, wN2, wD1);

  // ---- CSR build (self-loop +1 folded into scans) ----
  hipLaunchKernelGGL(k_count_edges, dim3((E + TPB - 1) / TPB), dim3(TPB), 0, stream, e_dst, E, cnt);
  hipLaunchKernelGGL(k_scan_bsum, dim3(NBLK_SCAN), dim3(256), 0, stream, cnt, N, bsum);
  hipLaunchKernelGGL(k_scan_offsets, dim3(1), dim3(64), 0, stream, bsum, NBLK_SCAN);
  hipLaunchKernelGGL(k_scan_final, dim3(NBLK_SCAN), dim3(256), 0, stream, cnt, N, bsum, indptr, esrc);
  hipLaunchKernelGGL(k_csr_fill, dim3((E + TPB - 1) / TPB), dim3(TPB), 0, stream, e_src, e_dst, E, cnt, esrc);
  hipLaunchKernelGGL(k_batch_starts, dim3((N + TPB - 1) / TPB), dim3(TPB), 0, stream, batch, N, BBATCH, starts);

  // ---- encoder ----
  hipLaunchKernelGGL(k_encoder, dim3((N * 64 + TPB - 1) / TPB), dim3(TPB), 0, stream,
                     x, enc_W, enc_b, h, N);

  const int GN = (N + 63) / 64;  // 782

  for (int l = 0; l < NLAYER; l++) {
    const unsigned short* LRt = wLR + (size_t)l * 512 * 64;
    const unsigned short* F1t = wF1 + (size_t)l * 128 * 64;
    const unsigned short* F2t = wF2 + (size_t)l * 64 * 128;
    const unsigned short* N1t = wN1 + (size_t)l * 64 * 64;
    const unsigned short* N2t = wN2 + (size_t)l * 64 * 64;
    const float* attl = gat_att + (size_t)l * 256;
    const float* gbl = gat_b + (size_t)l * 64;
    const float* lngl = ln_g + (size_t)l * 64;
    const float* lnbl = ln_b + (size_t)l * 64;
    const float* fb1 = ffn_b1 + (size_t)l * 128;
    const float* fb2 = ffn_b2 + (size_t)l * 64;
    const float* nb1 = n2g_b1 + (size_t)l * 64;
    const float* nb2 = n2g_b2 + (size_t)l * 64;
    const float* gW1 = g2n_W1 + (size_t)l * 128 * 64;
    const float* gb1 = g2n_b1 + (size_t)l * 64;
    const float* gW2 = g2n_W2 + (size_t)l * 64 * 64;
    const float* gb2 = g2n_b2 + (size_t)l * 64;
    float* psumL = psum_all + (size_t)l * BBATCH * 64;
    unsigned int* pmaxL = pmax_all + (size_t)l * BBATCH * 64;

    // xlr = (h [+ctx_{l-1}]) @ [Wl|Wr]
    if (l == 0)
      hipLaunchKernelGGL((k_xlr<false>), dim3(GN), dim3(256), 0, stream,
                         h, nullptr, nullptr, LRt, xlr, N);
    else
      hipLaunchKernelGGL((k_xlr<true>), dim3(GN), dim3(256), 0, stream,
                         h, ctx, batch, LRt, xlr, N);
    // GAT aggregate + residual(+ctx) + LN -> h2b
    if (l == 0)
      hipLaunchKernelGGL((k_gat<false>), dim3((N + 3) / 4), dim3(256), 0, stream,
                         xlr, attl, gbl, lngl, lnbl, h, nullptr, nullptr, indptr, esrc, h2b, N);
    else
      hipLaunchKernelGGL((k_gat<true>), dim3((N + 3) / 4), dim3(256), 0, stream,
                         xlr, attl, gbl, lngl, lnbl, h, ctx, batch, indptr, esrc, h2b, N);
    // fused FFN + n2g + pooling + last-block ctx MLP -> h, ctx
    hipLaunchKernelGGL(k_fnp, dim3(GN), dim3(256), 0, stream,
                       h2b, F1t, fb1, F2t, fb2, h,
                       N1t, nb1, N2t, nb2, batch, psumL, pmaxL,
                       gW1, gb1, gW2, gb2, starts, done + l, ctx, N);
  }

  // fused decoder (adds final ctx)
  hipLaunchKernelGGL(k_dec, dim3(GN), dim3(256), 0, stream,
                     h, ctx, batch, wD1, dec_b1, dec_W2, dec_b2, (float*)d_out, N);
}

// Round 13
// 829.438 us; speedup vs baseline: 1.3201x; 1.3201x over previous
//
#include <hip/hip_runtime.h>
#include <hip/hip_bf16.h>
#include <math.h>

#define NN 50000
#define EE 800000
#define BBATCH 64
#define DDIM 64
#define NLAYER 4
#define NIN 7
#define NHEAD 4

typedef __attribute__((ext_vector_type(8))) short short8v;   // 8 bf16 (4 VGPRs)
typedef __attribute__((ext_vector_type(4))) float f32x4;     // mfma acc

// ---------------- device helpers ----------------
static __device__ __forceinline__ float wave_sum(float v) {
#pragma unroll
  for (int m = 32; m > 0; m >>= 1) v += __shfl_xor(v, m, 64);
  return v;
}

static __device__ __forceinline__ float gelu_t(float x) {
  float z = 0.7978845608f * (x + 0.044715f * x * x * x);
  float t = 2.f / (1.f + __expf(-2.f * z)) - 1.f;
  return 0.5f * x * (1.f + t);
}

static __device__ __forceinline__ unsigned short f2b(float v) {
  __hip_bfloat16 b = __float2bfloat16(v);
  return *reinterpret_cast<unsigned short*>(&b);
}

static __device__ __forceinline__ float b2f(unsigned short u) {
  return __builtin_bit_cast(float, (unsigned int)u << 16);
}

// order-preserving float -> uint key (0 is below every real key)
static __device__ __forceinline__ unsigned fkey(float x) {
  unsigned u = __builtin_bit_cast(unsigned, x);
  return (u >> 31) ? ~u : (u | 0x80000000u);
}
static __device__ __forceinline__ float fkey_inv(unsigned k) {
  unsigned u = (k & 0x80000000u) ? (k ^ 0x80000000u) : ~k;
  return __builtin_bit_cast(float, u);
}

// cross-lane add via DPP (VALU pipe, no LDS)
template <int CTRL>
static __device__ __forceinline__ float dppf(float v) {
  int x = __builtin_amdgcn_mov_dpp(__builtin_bit_cast(int, v), CTRL, 0xF, 0xF, true);
  return __builtin_bit_cast(float, x);
}
// quad_perm [1,0,3,2]=0xB1 (xor1), [2,3,0,1]=0x4E (xor2), row_ror:4=0x124, row_ror:8=0x128

static __device__ __forceinline__ void unpack8(uint4 u, float* xs) {
  unsigned int w[4] = {u.x, u.y, u.z, u.w};
#pragma unroll
  for (int k = 0; k < 4; k++) {
    xs[2 * k]     = __builtin_bit_cast(float, w[k] << 16);
    xs[2 * k + 1] = __builtin_bit_cast(float, w[k] & 0xFFFF0000u);
  }
}

static __device__ __forceinline__ short8v pack8(const float* v) {
  short8v r;
#pragma unroll
  for (int j = 0; j < 8; j++) r[j] = (short)f2b(v[j]);
  return r;
}

// ---------------- CSR build ----------------
__global__ void k_count_edges(const int* __restrict__ dst, int e, int* cnt) {
  int i = blockIdx.x * blockDim.x + threadIdx.x;
  if (i < e) atomicAdd(&cnt[dst[i]], 1);
}

// per-1024 chunk sums; +1 per node folds the self loop (cnt zero-initialized)
__global__ void k_scan_bsum(const int* __restrict__ cnt, int n, int* bsum) {
  __shared__ int red[256];
  int b = blockIdx.x, t = threadIdx.x;
  int s = 0;
  for (int i = b * 1024 + t; i < (b + 1) * 1024; i += 256)
    if (i < n) s += cnt[i] + 1;
  red[t] = s;
  __syncthreads();
  for (int o = 128; o > 0; o >>= 1) {
    if (t < o) red[t] += red[t + o];
    __syncthreads();
  }
  if (t == 0) bsum[b] = red[0];
}

__global__ void k_scan_offsets(int* bsum, int nb) {
  if (threadIdx.x == 0 && blockIdx.x == 0) {
    int acc = 0;
    for (int i = 0; i < nb; i++) { int v = bsum[i]; bsum[i] = acc; acc += v; }
  }
}

// scan + self-loop insert fused (nxt aliases cnt); +1 per node folded
__global__ void k_scan_final(int* __restrict__ cnt, int n,
                             const int* __restrict__ bsum, int* __restrict__ indptr,
                             int* __restrict__ esrc) {
  __shared__ int lds[256];
  int b = blockIdx.x, t = threadIdx.x;
  int base = b * 1024;
  int v[4];
  int s = 0;
#pragma unroll
  for (int j = 0; j < 4; j++) {
    int i = base + t * 4 + j;
    v[j] = (i < n) ? cnt[i] + 1 : 0;
    s += v[j];
  }
  lds[t] = s;
  __syncthreads();
  for (int o = 1; o < 256; o <<= 1) {
    int x = (t >= o) ? lds[t - o] : 0;
    __syncthreads();
    lds[t] += x;
    __syncthreads();
  }
  int run = bsum[b] + lds[t] - s;
#pragma unroll
  for (int j = 0; j < 4; j++) {
    int i = base + t * 4 + j;
    if (i < n) {
      indptr[i] = run;
      esrc[run] = i;       // self loop first
      cnt[i] = run + 1;    // cnt becomes nxt
    } else if (i == n) {
      indptr[n] = run;
    }
    run += v[j];
  }
}

__global__ void k_csr_fill(const int* __restrict__ src, const int* __restrict__ dst,
                           int e, int* nxt, int* esrc) {
  int i = blockIdx.x * blockDim.x + threadIdx.x;
  if (i < e) {
    int p = atomicAdd(&nxt[dst[i]], 1);
    esrc[p] = src[i];
  }
}

// ---------------- batch segment starts (batch is sorted) ----------------
__global__ void k_batch_starts(const int* __restrict__ batch, int n, int nb, int* starts) {
  int i = blockIdx.x * blockDim.x + threadIdx.x;
  if (i >= n) return;
  int b = batch[i];
  if (i == 0) {
    for (int x = 0; x <= b; x++) starts[x] = 0;
  } else {
    int pb = batch[i - 1];
    if (pb != b)
      for (int x = pb + 1; x <= b; x++) starts[x] = i;
  }
  if (i == n - 1) {
    for (int x = b + 1; x <= nb; x++) starts[x] = n;
  }
}

// ---------------- merged weight prep ----------------
#define SEG_LR (4 * 512 * 64)
#define SEG_F1 (4 * 128 * 64)
#define SEG_F2 (4 * 64 * 128)
#define SEG_N  (4 * 64 * 64)
#define SEG_D  (64 * 64)
#define WPREP_TOTAL (SEG_LR + SEG_F1 + SEG_F2 + 2 * SEG_N + SEG_D)
__global__ void k_wprep_all(const float* __restrict__ Wl, const float* __restrict__ Wr,
                            const float* __restrict__ F1, const float* __restrict__ F2,
                            const float* __restrict__ N1, const float* __restrict__ N2,
                            const float* __restrict__ D1,
                            unsigned short* __restrict__ wLR, unsigned short* __restrict__ wF1,
                            unsigned short* __restrict__ wF2, unsigned short* __restrict__ wN1,
                            unsigned short* __restrict__ wN2, unsigned short* __restrict__ wD1) {
  int idx = blockIdx.x * blockDim.x + threadIdx.x;
  if (idx < SEG_LR) {
    int l = idx / (512 * 64), rem = idx % (512 * 64);
    int c = rem / 64, k = rem % 64;
    float v = (c < 256) ? Wl[(size_t)l * 64 * 256 + k * 256 + c]
                        : Wr[(size_t)l * 64 * 256 + k * 256 + (c - 256)];
    wLR[idx] = f2b(v);
    return;
  }
  idx -= SEG_LR;
  if (idx < SEG_F1) {
    int l = idx / (128 * 64), rem = idx % (128 * 64);
    int c = rem / 64, k = rem % 64;
    wF1[idx] = f2b(F1[(size_t)l * 64 * 128 + k * 128 + c]);
    return;
  }
  idx -= SEG_F1;
  if (idx < SEG_F2) {
    int l = idx / (64 * 128), rem = idx % (64 * 128);
    int c = rem / 128, k = rem % 128;
    wF2[idx] = f2b(F2[(size_t)l * 128 * 64 + k * 64 + c]);
    return;
  }
  idx -= SEG_F2;
  if (idx < SEG_N) {
    int l = idx / (64 * 64), rem = idx % (64 * 64);
    int c = rem / 64, k = rem % 64;
    wN1[idx] = f2b(N1[(size_t)l * 64 * 64 + k * 64 + c]);
    return;
  }
  idx -= SEG_N;
  if (idx < SEG_N) {
    int l = idx / (64 * 64), rem = idx % (64 * 64);
    int c = rem / 64, k = rem % 64;
    wN2[idx] = f2b(N2[(size_t)l * 64 * 64 + k * 64 + c]);
    return;
  }
  idx -= SEG_N;
  if (idx < SEG_D) {
    int c = idx / 64, k = idx % 64;
    wD1[idx] = f2b(D1[k * 64 + c]);
  }
}

// ---------------- encoder (fp32 h only) ----------------
__global__ void k_encoder(const float* __restrict__ x, const float* __restrict__ W,
                          const float* __restrict__ bias, float* __restrict__ h, int n) {
  int idx = blockIdx.x * blockDim.x + threadIdx.x;
  if (idx >= n * 64) return;
  int i = idx >> 6, d = idx & 63;
  float acc = bias[d];
#pragma unroll
  for (int k = 0; k < NIN; k++) acc += x[i * NIN + k] * W[k * 64 + d];
  h[idx] = acc;
}

// ---------------- xlr GEMM: xlr = (h [+ctx]) @ [Wl|Wr], bf16 out, Co=512 ----------------
template <bool CTX>
__global__ __launch_bounds__(256) void k_xlr(const float* __restrict__ A,
                                             const float* __restrict__ ctxv,
                                             const int* __restrict__ batch,
                                             const unsigned short* __restrict__ Wt,
                                             unsigned short* __restrict__ Cb, int n) {
  const int lane = threadIdx.x & 63, wave = threadIdx.x >> 6;
  const int row0 = blockIdx.x * 64 + wave * 16;
  const int karow = (lane >> 4) * 8;
  const int arow0 = row0 + (lane & 15);
  const int arow = arow0 < n ? arow0 : 0;
  const float* ap = A + (size_t)arow * 64;

  float av[16];
  {
    float4 f0 = *(const float4*)(ap + karow);
    float4 f1 = *(const float4*)(ap + karow + 4);
    float4 f2 = *(const float4*)(ap + 32 + karow);
    float4 f3 = *(const float4*)(ap + 32 + karow + 4);
    av[0] = f0.x; av[1] = f0.y; av[2] = f0.z; av[3] = f0.w;
    av[4] = f1.x; av[5] = f1.y; av[6] = f1.z; av[7] = f1.w;
    av[8] = f2.x; av[9] = f2.y; av[10] = f2.z; av[11] = f2.w;
    av[12] = f3.x; av[13] = f3.y; av[14] = f3.z; av[15] = f3.w;
    if (CTX) {
      const float* cp = ctxv + batch[arow] * 64;
      float4 c0v = *(const float4*)(cp + karow);
      float4 c1v = *(const float4*)(cp + karow + 4);
      float4 c2v = *(const float4*)(cp + 32 + karow);
      float4 c3v = *(const float4*)(cp + 32 + karow + 4);
      av[0] += c0v.x; av[1] += c0v.y; av[2] += c0v.z; av[3] += c0v.w;
      av[4] += c1v.x; av[5] += c1v.y; av[6] += c1v.z; av[7] += c1v.w;
      av[8] += c2v.x; av[9] += c2v.y; av[10] += c2v.z; av[11] += c2v.w;
      av[12] += c3v.x; av[13] += c3v.y; av[14] += c3v.z; av[15] += c3v.w;
    }
  }
  short8v a0 = pack8(av), a1 = pack8(av + 8);

#pragma unroll
  for (int cb = 0; cb < 8; cb++) {
#pragma unroll
    for (int cc = 0; cc < 4; cc++) {
      const int c = cb * 64 + cc * 16 + (lane & 15);
      f32x4 t = {0.f, 0.f, 0.f, 0.f};
      t = __builtin_amdgcn_mfma_f32_16x16x32_bf16(a0, *(const short8v*)(Wt + (size_t)c * 64 + karow), t, 0, 0, 0);
      t = __builtin_amdgcn_mfma_f32_16x16x32_bf16(a1, *(const short8v*)(Wt + (size_t)c * 64 + 32 + karow), t, 0, 0, 0);
#pragma unroll
      for (int r = 0; r < 4; r++) {
        const int row = row0 + (lane >> 4) * 4 + r;
        if (row < n) Cb[(size_t)row * 512 + c] = f2b(t[r]);
      }
    }
  }
}

// ---------------- fused FFN + n2g + pooling (round-10 structure, bf16 residual) --------
__global__ __launch_bounds__(256) void k_fnp(const unsigned short* __restrict__ A,   // h2b
                                             const unsigned short* __restrict__ F1t, // [128][64]
                                             const float* __restrict__ fb1,
                                             const unsigned short* __restrict__ F2t, // [64][128]
                                             const float* __restrict__ fb2,
                                             float* __restrict__ hOut,
                                             const unsigned short* __restrict__ N1t, // [64][64]
                                             const float* __restrict__ nb1,
                                             const unsigned short* __restrict__ N2t, // [64][64]
                                             const float* __restrict__ nb2,
                                             const int* __restrict__ batch,
                                             float* __restrict__ psum,
                                             unsigned int* __restrict__ pmax, int n) {
  __shared__ unsigned short tl[4][16 * 136];  // FFN mid (16x128), reused n2g mid (@72)
  __shared__ unsigned short tn[4][16 * 72];   // n2g input (16x64 @72)
  __shared__ float s_sum[64];
  __shared__ unsigned s_max[64];
  const int lane = threadIdx.x & 63, wave = threadIdx.x >> 6;
  const int row0b = blockIdx.x * 64;
  const int row0 = row0b + wave * 16;
  const int karow = (lane >> 4) * 8;
  const int arow = row0 + (lane & 15);
  const size_t abase = (size_t)(arow < n ? arow : 0) * 64 + karow;
  if (threadIdx.x < 64) { s_sum[threadIdx.x] = 0.f; s_max[threadIdx.x] = 0u; }
  short8v a0 = *(const short8v*)(A + abase);
  short8v a1 = *(const short8v*)(A + abase + 32);

  // ---- FFN stage 1: 64 -> 128, leaky, to tl (stride 136) ----
#pragma unroll
  for (int cc = 0; cc < 8; cc++) {
    const int c = cc * 16 + (lane & 15);
    f32x4 t = {0.f, 0.f, 0.f, 0.f};
    t = __builtin_amdgcn_mfma_f32_16x16x32_bf16(a0, *(const short8v*)(F1t + (size_t)c * 64 + karow), t, 0, 0, 0);
    t = __builtin_amdgcn_mfma_f32_16x16x32_bf16(a1, *(const short8v*)(F1t + (size_t)c * 64 + 32 + karow), t, 0, 0, 0);
    const float bv = fb1[c];
#pragma unroll
    for (int r = 0; r < 4; r++) {
      float v = t[r] + bv;
      v = fmaxf(v, 0.2f * v);
      int rr = (lane >> 4) * 4 + r;
      tl[wave][rr * 136 + c] = f2b(v);
    }
  }

  // ---- FFN stage 2: 128 -> 64, +bias +res(bf16 from A) -> h fp32; bf16 to tn ----
  short8v a2[4];
#pragma unroll
  for (int f = 0; f < 4; f++)
    a2[f] = *(const short8v*)(&tl[wave][(lane & 15) * 136 + f * 32 + karow]);

#pragma unroll
  for (int cc = 0; cc < 4; cc++) {
    const int c = cc * 16 + (lane & 15);
    f32x4 t = {0.f, 0.f, 0.f, 0.f};
#pragma unroll
    for (int f = 0; f < 4; f++)
      t = __builtin_amdgcn_mfma_f32_16x16x32_bf16(a2[f], *(const short8v*)(F2t + (size_t)c * 128 + f * 32 + karow), t, 0, 0, 0);
    const float bv = fb2[c];
#pragma unroll
    for (int r = 0; r < 4; r++) {
      const int row = row0 + (lane >> 4) * 4 + r;
      const int rr = (lane >> 4) * 4 + r;
      float v = t[r] + bv + ((row < n) ? b2f(A[(size_t)row * 64 + c]) : 0.f);
      if (row < n) hOut[(size_t)row * 64 + c] = v;
      tn[wave][rr * 72 + c] = f2b(v);
    }
  }

  // ---- n2g stage 1: 64 -> 64, gelu, to tl (@72) ----
  short8v a3[2];
#pragma unroll
  for (int f = 0; f < 2; f++)
    a3[f] = *(const short8v*)(&tn[wave][(lane & 15) * 72 + f * 32 + karow]);

#pragma unroll
  for (int cc = 0; cc < 4; cc++) {
    const int c = cc * 16 + (lane & 15);
    f32x4 t = {0.f, 0.f, 0.f, 0.f};
    t = __builtin_amdgcn_mfma_f32_16x16x32_bf16(a3[0], *(const short8v*)(N1t + (size_t)c * 64 + karow), t, 0, 0, 0);
    t = __builtin_amdgcn_mfma_f32_16x16x32_bf16(a3[1], *(const short8v*)(N1t + (size_t)c * 64 + 32 + karow), t, 0, 0, 0);
    const float bv = nb1[c];
#pragma unroll
    for (int r = 0; r < 4; r++) {
      int rr = (lane >> 4) * 4 + r;
      tl[wave][rr * 72 + c] = f2b(gelu_t(t[r] + bv));
    }
  }

  // ---- n2g stage 2: 64 -> 64 -> pv ----
  short8v a4[2];
#pragma unroll
  for (int f = 0; f < 2; f++)
    a4[f] = *(const short8v*)(&tl[wave][(lane & 15) * 72 + f * 32 + karow]);

  float pv[4][4];
#pragma unroll
  for (int cc = 0; cc < 4; cc++) {
    const int c = cc * 16 + (lane & 15);
    f32x4 t = {0.f, 0.f, 0.f, 0.f};
    t = __builtin_amdgcn_mfma_f32_16x16x32_bf16(a4[0], *(const short8v*)(N2t + (size_t)c * 64 + karow), t, 0, 0, 0);
    t = __builtin_amdgcn_mfma_f32_16x16x32_bf16(a4[1], *(const short8v*)(N2t + (size_t)c * 64 + 32 + karow), t, 0, 0, 0);
    const float bv = nb2[c];
#pragma unroll
    for (int r = 0; r < 4; r++) pv[cc][r] = t[r] + bv;
  }

  // ---- pooling epilogue ----
  __syncthreads();  // s_sum/s_max init visible
  const int blo = batch[row0b];
  const int last = row0b + 63 < n ? row0b + 63 : n - 1;
  const int bhi = batch[last];
  if (blo == bhi && row0b + 63 < n) {
#pragma unroll
    for (int cc = 0; cc < 4; cc++) {
      const int c = cc * 16 + (lane & 15);
      float s = pv[cc][0] + pv[cc][1] + pv[cc][2] + pv[cc][3];
      float mx = fmaxf(fmaxf(pv[cc][0], pv[cc][1]), fmaxf(pv[cc][2], pv[cc][3]));
      atomicAdd(&s_sum[c], s);
      atomicMax(&s_max[c], fkey(mx));
    }
    __syncthreads();
    if (threadIdx.x < 64) {
      atomicAdd(&psum[blo * 64 + threadIdx.x], s_sum[threadIdx.x]);
      atomicMax(&pmax[blo * 64 + threadIdx.x], s_max[threadIdx.x]);
    }
  } else {
#pragma unroll
    for (int cc = 0; cc < 4; cc++) {
      const int c = cc * 16 + (lane & 15);
#pragma unroll
      for (int r = 0; r < 4; r++) {
        const int row = row0 + (lane >> 4) * 4 + r;
        if (row < n) {
          const int b = batch[row];
          atomicAdd(&psum[b * 64 + c], pv[cc][r]);
          atomicMax(&pmax[b * 64 + c], fkey(pv[cc][r]));
        }
      }
    }
  }
}

// ---------------- GATv2 aggregation + residual(+ctx) + LayerNorm (bf16 out only) -------
template <bool CTX>
__global__ __launch_bounds__(256) void k_gat(const unsigned short* __restrict__ xlr,
                                             const float* __restrict__ att,
                                             const float* __restrict__ gbias,
                                             const float* __restrict__ lng,
                                             const float* __restrict__ lnb,
                                             const float* __restrict__ h,
                                             const float* __restrict__ ctxv,
                                             const int* __restrict__ batch,
                                             const int* __restrict__ indptr,
                                             const int* __restrict__ esrc,
                                             unsigned short* __restrict__ h2b, int n) {
  const int wave = threadIdx.x >> 6, lane = threadIdx.x & 63;
  const int node = blockIdx.x * 4 + wave;
  if (node >= n) return;
  const int q = lane >> 4, r = lane & 15;
  const int c = r & 3;
  const int doff = (r >> 2) * 64 + c * 16;

  float xr_d[16], att_d[16];
  {
    const uint4* xp = (const uint4*)(xlr + (size_t)node * 512 + 256 + doff);
    uint4 u0 = xp[0], u1 = xp[1];
    unpack8(u0, xr_d);
    unpack8(u1, xr_d + 8);
    const float4* ap = (const float4*)(att + doff);
#pragma unroll
    for (int k = 0; k < 4; k++) {
      float4 a = ap[k];
      att_d[4 * k] = a.x; att_d[4 * k + 1] = a.y;
      att_d[4 * k + 2] = a.z; att_d[4 * k + 3] = a.w;
    }
  }

  float acc[16] = {};
  float den = 0.f;
  const int beg = indptr[node], end = indptr[node + 1];

  // 2-deep pipeline: data 1 ahead, esrc index 2 ahead
  int j0 = beg + q;
  int s_cur = esrc[(j0 < end) ? j0 : beg];
  const uint4* xp0 = (const uint4*)(xlr + (size_t)s_cur * 512 + doff);
  uint4 u0 = xp0[0], u1 = xp0[1];
  int jn1 = beg + 4 + q;
  int s_nxt = esrc[(jn1 < end && beg + 4 < end) ? jn1 : beg];

  for (int jb = beg; jb < end; jb += 4) {
    const uint4 cu0 = u0, cu1 = u1;
    const bool cvalid = (jb + q) < end;
    if (jb + 4 < end) {
      const uint4* xpn = (const uint4*)(xlr + (size_t)s_nxt * 512 + doff);
      u0 = xpn[0];
      u1 = xpn[1];
      if (jb + 8 < end) {
        const int jn = jb + 8 + q;
        s_nxt = esrc[(jn < end) ? jn : beg];
      }
    }
    float xs[16];
    unpack8(cu0, xs);
    unpack8(cu1, xs + 8);
    float p0 = 0.f, p1 = 0.f, p2 = 0.f, p3 = 0.f;
#pragma unroll
    for (int k = 0; k < 4; k++) {
      float t0 = xs[4 * k + 0] + xr_d[4 * k + 0]; t0 = fmaxf(t0, 0.2f * t0); p0 = fmaf(t0, att_d[4 * k + 0], p0);
      float t1 = xs[4 * k + 1] + xr_d[4 * k + 1]; t1 = fmaxf(t1, 0.2f * t1); p1 = fmaf(t1, att_d[4 * k + 1], p1);
      float t2 = xs[4 * k + 2] + xr_d[4 * k + 2]; t2 = fmaxf(t2, 0.2f * t2); p2 = fmaf(t2, att_d[4 * k + 2], p2);
      float t3 = xs[4 * k + 3] + xr_d[4 * k + 3]; t3 = fmaxf(t3, 0.2f * t3); p3 = fmaf(t3, att_d[4 * k + 3], p3);
    }
    float p = (p0 + p1) + (p2 + p3);
    p += dppf<0xB1>(p);
    p += dppf<0x4E>(p);
    const float pw = cvalid ? __expf(fminf(p, 60.f)) : 0.f;
    den += pw;
#pragma unroll
    for (int d = 0; d < 16; d++) acc[d] = fmaf(pw, xs[d], acc[d]);
  }

  den += __shfl_xor(den, 16, 64);
  den += __shfl_xor(den, 32, 64);
#pragma unroll
  for (int d = 0; d < 16; d++) {
    acc[d] += __shfl_xor(acc[d], 16, 64);
    acc[d] += __shfl_xor(acc[d], 32, 64);
  }

  const float rden = 0.25f / (den + 1e-16f);
  float y[16];
  float s4 = 0.f;
  const float4* hp = (const float4*)(h + (size_t)node * 64 + c * 16);
  const float4* gp = (const float4*)(gbias + c * 16);
  const float4* cp = CTX ? (const float4*)(ctxv + batch[node] * 64 + c * 16) : nullptr;
#pragma unroll
  for (int k = 0; k < 4; k++) {
    float4 hv = hp[k], gv = gp[k];
    if (CTX) {
      float4 cv = cp[k];
      hv.x += cv.x; hv.y += cv.y; hv.z += cv.z; hv.w += cv.w;
    }
    float hf[4] = {hv.x, hv.y, hv.z, hv.w};
    float gf[4] = {gv.x, gv.y, gv.z, gv.w};
#pragma unroll
    for (int d2 = 0; d2 < 4; d2++) {
      int d = 4 * k + d2;
      float v = acc[d] * rden;
      v += dppf<0x124>(v);
      v += dppf<0x128>(v);
      y[d] = hf[d2] + v + gf[d2];
      s4 += y[d];
    }
  }

  const float mu = wave_sum(s4) * (1.f / 1024.f);
  float v4 = 0.f;
  float dv[16];
#pragma unroll
  for (int d = 0; d < 16; d++) {
    dv[d] = y[d] - mu;
    v4 += dv[d] * dv[d];
  }
  const float var = wave_sum(v4) * (1.f / 1024.f);
  const float rstd = rsqrtf(var + 1e-5f);

  if (lane < 4) {
    uint2* outb = (uint2*)(h2b + (size_t)node * 64 + lane * 16);
    const float4* lgp = (const float4*)(lng + lane * 16);
    const float4* lbp = (const float4*)(lnb + lane * 16);
#pragma unroll
    for (int k = 0; k < 4; k++) {
      float4 g = lgp[k], b = lbp[k];
      float o0 = dv[4 * k + 0] * rstd * g.x + b.x;
      float o1 = dv[4 * k + 1] * rstd * g.y + b.y;
      float o2 = dv[4 * k + 2] * rstd * g.z + b.z;
      float o3 = dv[4 * k + 3] * rstd * g.w + b.w;
      uint2 pk;
      pk.x = (unsigned int)f2b(o0) | ((unsigned int)f2b(o1) << 16);
      pk.y = (unsigned int)f2b(o2) | ((unsigned int)f2b(o3) << 16);
      outb[k] = pk;
    }
  }
}

// ---------------- ctx MLP from pooled psum/pmax ----------------
__global__ void k_ctx2(const float* __restrict__ psum, const unsigned int* __restrict__ pmax,
                       const int* __restrict__ starts,
                       const float* __restrict__ W1, const float* __restrict__ b1,
                       const float* __restrict__ W2, const float* __restrict__ b2,
                       float* __restrict__ ctx) {
  int b = blockIdx.x;
  int t = threadIdx.x;  // 128 threads
  __shared__ float g[128], tt[64];
  int cnt = starts[b + 1] - starts[b];
  if (t < 64) {
    g[t] = psum[b * 64 + t] / fmaxf((float)cnt, 1.0f);
  } else {
    g[t] = fkey_inv(pmax[b * 64 + (t - 64)]);
  }
  __syncthreads();
  if (t < 64) {
    float acc = b1[t];
    for (int k = 0; k < 128; k++) acc += g[k] * W1[k * 64 + t];
    tt[t] = gelu_t(acc);
  }
  __syncthreads();
  if (t < 64) {
    float acc2 = b2[t];
    for (int k = 0; k < 64; k++) acc2 += tt[k] * W2[k * 64 + t];
    ctx[b * 64 + t] = acc2;
  }
}

// ---------------- fused decoder: out = gelu((h+ctx)@W1+b1)@W2 + b2 ----------------
__global__ __launch_bounds__(256) void k_dec(const float* __restrict__ A,            // h fp32
                                             const float* __restrict__ ctxv,
                                             const int* __restrict__ batch,
                                             const unsigned short* __restrict__ W1t,
                                             const float* __restrict__ b1,
                                             const float* __restrict__ W2,
                                             const float* __restrict__ b2,
                                             float* __restrict__ out, int n) {
  const int lane = threadIdx.x & 63, wave = threadIdx.x >> 6;
  const int row0 = blockIdx.x * 64 + wave * 16;
  const int karow = (lane >> 4) * 8;
  const int arow0 = row0 + (lane & 15);
  const int arow = arow0 < n ? arow0 : 0;
  const float* ap = A + (size_t)arow * 64;
  const float* cp = ctxv + batch[arow] * 64;

  float av[16];
  {
    float4 f0 = *(const float4*)(ap + karow);
    float4 f1 = *(const float4*)(ap + karow + 4);
    float4 f2 = *(const float4*)(ap + 32 + karow);
    float4 f3 = *(const float4*)(ap + 32 + karow + 4);
    float4 c0v = *(const float4*)(cp + karow);
    float4 c1v = *(const float4*)(cp + karow + 4);
    float4 c2v = *(const float4*)(cp + 32 + karow);
    float4 c3v = *(const float4*)(cp + 32 + karow + 4);
    av[0] = f0.x + c0v.x; av[1] = f0.y + c0v.y; av[2] = f0.z + c0v.z; av[3] = f0.w + c0v.w;
    av[4] = f1.x + c1v.x; av[5] = f1.y + c1v.y; av[6] = f1.z + c1v.z; av[7] = f1.w + c1v.w;
    av[8] = f2.x + c2v.x; av[9] = f2.y + c2v.y; av[10] = f2.z + c2v.z; av[11] = f2.w + c2v.w;
    av[12] = f3.x + c3v.x; av[13] = f3.y + c3v.y; av[14] = f3.z + c3v.z; av[15] = f3.w + c3v.w;
  }
  short8v a0 = pack8(av), a1 = pack8(av + 8);

  float o0[4] = {}, o1[4] = {};
#pragma unroll
  for (int cc = 0; cc < 4; cc++) {
    const int cidx = cc * 16 + (lane & 15);
    f32x4 t = {0.f, 0.f, 0.f, 0.f};
    t = __builtin_amdgcn_mfma_f32_16x16x32_bf16(a0, *(const short8v*)(W1t + (size_t)cidx * 64 + karow), t, 0, 0, 0);
    t = __builtin_amdgcn_mfma_f32_16x16x32_bf16(a1, *(const short8v*)(W1t + (size_t)cidx * 64 + 32 + karow), t, 0, 0, 0);
    const float bv = b1[cidx];
    const float w0 = W2[cidx * 2 + 0], w1 = W2[cidx * 2 + 1];
#pragma unroll
    for (int r = 0; r < 4; r++) {
      float v = gelu_t(t[r] + bv);
      o0[r] = fmaf(v, w0, o0[r]);
      o1[r] = fmaf(v, w1, o1[r]);
    }
  }
#pragma unroll
  for (int m = 1; m < 16; m <<= 1) {
#pragma unroll
    for (int r = 0; r < 4; r++) {
      o0[r] += __shfl_xor(o0[r], m, 64);
      o1[r] += __shfl_xor(o1[r], m, 64);
    }
  }
  if ((lane & 15) == 0) {
#pragma unroll
    for (int r = 0; r < 4; r++) {
      const int row = row0 + (lane >> 4) * 4 + r;
      if (row < n) {
        out[2 * row] = o0[r] + b2[0];
        out[2 * row + 1] = o1[r] + b2[1];
      }
    }
  }
}

// ---------------- host ----------------
extern "C" void kernel_launch(void* const* d_in, const int* in_sizes, int n_in,
                              void* d_out, int out_size, void* d_ws, size_t ws_size,
                              hipStream_t stream) {
  const float* x = (const float*)d_in[0];
  const int* ei = (const int*)d_in[1];
  const int* batch = (const int*)d_in[2];
  const float* enc_W = (const float*)d_in[3];
  const float* enc_b = (const float*)d_in[4];
  const float* gat_Wl = (const float*)d_in[5];
  const float* gat_Wr = (const float*)d_in[6];
  const float* gat_att = (const float*)d_in[7];
  const float* gat_b = (const float*)d_in[8];
  const float* ln_g = (const float*)d_in[9];
  const float* ln_b = (const float*)d_in[10];
  const float* ffn_W1 = (const float*)d_in[11];
  const float* ffn_b1 = (const float*)d_in[12];
  const float* ffn_W2 = (const float*)d_in[13];
  const float* ffn_b2 = (const float*)d_in[14];
  const float* n2g_W1 = (const float*)d_in[15];
  const float* n2g_b1 = (const float*)d_in[16];
  const float* n2g_W2 = (const float*)d_in[17];
  const float* n2g_b2 = (const float*)d_in[18];
  const float* g2n_W1 = (const float*)d_in[19];
  const float* g2n_b1 = (const float*)d_in[20];
  const float* g2n_W2 = (const float*)d_in[21];
  const float* g2n_b2 = (const float*)d_in[22];
  const float* dec_W1 = (const float*)d_in[23];
  const float* dec_b1 = (const float*)d_in[24];
  const float* dec_W2 = (const float*)d_in[25];
  const float* dec_b2 = (const float*)d_in[26];

  const int N = NN, E = EE;
  const int* e_src = ei;
  const int* e_dst = ei + E;

  // ---- workspace carve ----
  // [psum_all | pmax_all | cnt] contiguous -> one upfront memset.
  float* h = (float*)d_ws;                    // N*64
  float* ctx = h + (size_t)N * 64;            // B*64
  float* psum_all = ctx + BBATCH * 64;        // 4 * B*64
  unsigned int* pmax_all = (unsigned int*)(psum_all + 4 * BBATCH * 64);  // 4 * B*64
  int* cnt = (int*)(pmax_all + 4 * BBATCH * 64);  // N (zero-init; becomes nxt)
  int* indptr = cnt + N;                      // N+1
  int* esrc = indptr + N + 1;                 // E+N
  int* bsum = esrc + (E + N);                 // 64
  int* starts = bsum + 64;                    // B+1
  size_t off = (size_t)(starts + BBATCH + 1) - (size_t)d_ws;
  off = (off + 15) & ~(size_t)15;
  unsigned short* h2b = (unsigned short*)((char*)d_ws + off);  // N*64
  unsigned short* xlr = h2b + (size_t)N * 64;                  // N*512 (xl | xr)
  unsigned short* wLR = xlr + (size_t)N * 512;                 // 4*512*64
  unsigned short* wF1 = wLR + SEG_LR;
  unsigned short* wF2 = wF1 + SEG_F1;
  unsigned short* wN1 = wF2 + SEG_F2;
  unsigned short* wN2 = wN1 + SEG_N;
  unsigned short* wD1 = wN2 + SEG_N;

  const int TPB = 256;
  const int NBLK_SCAN = (N + 1 + 1023) / 1024;

  // ---- zero psum/pmax/cnt in one memset ----
  hipMemsetAsync(psum_all, 0,
                 (size_t)4 * BBATCH * 64 * (sizeof(float) + sizeof(unsigned int)) +
                 (size_t)N * sizeof(int),
                 stream);

  // ---- weight prep (one dispatch) ----
  hipLaunchKernelGGL(k_wprep_all, dim3((WPREP_TOTAL + 255) / 256), dim3(256), 0, stream,
                     gat_Wl, gat_Wr, ffn_W1, ffn_W2, n2g_W1, n2g_W2, dec_W1,
                     wLR, wF1, wF2, wN1, wN2, wD1);

  // ---- CSR build (self-loop +1 folded into scans) ----
  hipLaunchKernelGGL(k_count_edges, dim3((E + TPB - 1) / TPB), dim3(TPB), 0, stream, e_dst, E, cnt);
  hipLaunchKernelGGL(k_scan_bsum, dim3(NBLK_SCAN), dim3(256), 0, stream, cnt, N, bsum);
  hipLaunchKernelGGL(k_scan_offsets, dim3(1), dim3(64), 0, stream, bsum, NBLK_SCAN);
  hipLaunchKernelGGL(k_scan_final, dim3(NBLK_SCAN), dim3(256), 0, stream, cnt, N, bsum, indptr, esrc);
  hipLaunchKernelGGL(k_csr_fill, dim3((E + TPB - 1) / TPB), dim3(TPB), 0, stream, e_src, e_dst, E, cnt, esrc);
  hipLaunchKernelGGL(k_batch_starts, dim3((N + TPB - 1) / TPB), dim3(TPB), 0, stream, batch, N, BBATCH, starts);

  // ---- encoder ----
  hipLaunchKernelGGL(k_encoder, dim3((N * 64 + TPB - 1) / TPB), dim3(TPB), 0, stream,
                     x, enc_W, enc_b, h, N);

  const int GN = (N + 63) / 64;  // 782

  for (int l = 0; l < NLAYER; l++) {
    const unsigned short* LRt = wLR + (size_t)l * 512 * 64;
    const unsigned short* F1t = wF1 + (size_t)l * 128 * 64;
    const unsigned short* F2t = wF2 + (size_t)l * 64 * 128;
    const unsigned short* N1t = wN1 + (size_t)l * 64 * 64;
    const unsigned short* N2t = wN2 + (size_t)l * 64 * 64;
    const float* attl = gat_att + (size_t)l * 256;
    const float* gbl = gat_b + (size_t)l * 64;
    const float* lngl = ln_g + (size_t)l * 64;
    const float* lnbl = ln_b + (size_t)l * 64;
    const float* fb1 = ffn_b1 + (size_t)l * 128;
    const float* fb2 = ffn_b2 + (size_t)l * 64;
    const float* nb1 = n2g_b1 + (size_t)l * 64;
    const float* nb2 = n2g_b2 + (size_t)l * 64;
    const float* gW1 = g2n_W1 + (size_t)l * 128 * 64;
    const float* gb1 = g2n_b1 + (size_t)l * 64;
    const float* gW2 = g2n_W2 + (size_t)l * 64 * 64;
    const float* gb2 = g2n_b2 + (size_t)l * 64;
    float* psumL = psum_all + (size_t)l * BBATCH * 64;
    unsigned int* pmaxL = pmax_all + (size_t)l * BBATCH * 64;

    // xlr = (h [+ctx_{l-1}]) @ [Wl|Wr]
    if (l == 0)
      hipLaunchKernelGGL((k_xlr<false>), dim3(GN), dim3(256), 0, stream,
                         h, nullptr, nullptr, LRt, xlr, N);
    else
      hipLaunchKernelGGL((k_xlr<true>), dim3(GN), dim3(256), 0, stream,
                         h, ctx, batch, LRt, xlr, N);
    // GAT aggregate + residual(+ctx) + LN -> h2b (bf16 only)
    if (l == 0)
      hipLaunchKernelGGL((k_gat<false>), dim3((N + 3) / 4), dim3(256), 0, stream,
                         xlr, attl, gbl, lngl, lnbl, h, nullptr, nullptr, indptr, esrc, h2b, N);
    else
      hipLaunchKernelGGL((k_gat<true>), dim3((N + 3) / 4), dim3(256), 0, stream,
                         xlr, attl, gbl, lngl, lnbl, h, ctx, batch, indptr, esrc, h2b, N);
    // fused FFN + n2g + pooling -> h, psum/pmax
    hipLaunchKernelGGL(k_fnp, dim3(GN), dim3(256), 0, stream,
                       h2b, F1t, fb1, F2t, fb2, h,
                       N1t, nb1, N2t, nb2, batch, psumL, pmaxL, N);
    // ctx MLP
    hipLaunchKernelGGL(k_ctx2, dim3(BBATCH), dim3(128), 0, stream,
                       psumL, pmaxL, starts, gW1, gb1, gW2, gb2, ctx);
  }

  // fused decoder (adds final ctx)
  hipLaunchKernelGGL(k_dec, dim3(GN), dim3(256), 0, stream,
                     h, ctx, batch, wD1, dec_b1, dec_W2, dec_b2, (float*)d_out, N);
}

// Round 14
// 827.494 us; speedup vs baseline: 1.3232x; 1.0024x over previous
//
#include <hip/hip_runtime.h>
#include <hip/hip_bf16.h>
#include <math.h>

#define NN 50000
#define EE 800000
#define BBATCH 64
#define DDIM 64
#define NLAYER 4
#define NIN 7
#define NHEAD 4

typedef __attribute__((ext_vector_type(8))) short short8v;   // 8 bf16 (4 VGPRs)
typedef __attribute__((ext_vector_type(4))) float f32x4;     // mfma acc

// ---------------- device helpers ----------------
static __device__ __forceinline__ float wave_sum(float v) {
#pragma unroll
  for (int m = 32; m > 0; m >>= 1) v += __shfl_xor(v, m, 64);
  return v;
}

static __device__ __forceinline__ float gelu_t(float x) {
  float z = 0.7978845608f * (x + 0.044715f * x * x * x);
  float t = 2.f / (1.f + __expf(-2.f * z)) - 1.f;
  return 0.5f * x * (1.f + t);
}

static __device__ __forceinline__ unsigned short f2b(float v) {
  __hip_bfloat16 b = __float2bfloat16(v);
  return *reinterpret_cast<unsigned short*>(&b);
}

static __device__ __forceinline__ float b2f(unsigned short u) {
  return __builtin_bit_cast(float, (unsigned int)u << 16);
}

// order-preserving float -> uint key (0 is below every real key)
static __device__ __forceinline__ unsigned fkey(float x) {
  unsigned u = __builtin_bit_cast(unsigned, x);
  return (u >> 31) ? ~u : (u | 0x80000000u);
}
static __device__ __forceinline__ float fkey_inv(unsigned k) {
  unsigned u = (k & 0x80000000u) ? (k ^ 0x80000000u) : ~k;
  return __builtin_bit_cast(float, u);
}

// cross-lane add via DPP (VALU pipe, no LDS)
template <int CTRL>
static __device__ __forceinline__ float dppf(float v) {
  int x = __builtin_amdgcn_mov_dpp(__builtin_bit_cast(int, v), CTRL, 0xF, 0xF, true);
  return __builtin_bit_cast(float, x);
}
// quad_perm [1,0,3,2]=0xB1 (xor1), [2,3,0,1]=0x4E (xor2), row_ror:4=0x124, row_ror:8=0x128

static __device__ __forceinline__ void unpack8(uint4 u, float* xs) {
  unsigned int w[4] = {u.x, u.y, u.z, u.w};
#pragma unroll
  for (int k = 0; k < 4; k++) {
    xs[2 * k]     = __builtin_bit_cast(float, w[k] << 16);
    xs[2 * k + 1] = __builtin_bit_cast(float, w[k] & 0xFFFF0000u);
  }
}

static __device__ __forceinline__ short8v pack8(const float* v) {
  short8v r;
#pragma unroll
  for (int j = 0; j < 8; j++) r[j] = (short)f2b(v[j]);
  return r;
}

// ---------------- CSR build ----------------
__global__ void k_count_edges(const int* __restrict__ dst, int e, int* cnt) {
  int i = blockIdx.x * blockDim.x + threadIdx.x;
  if (i < e) atomicAdd(&cnt[dst[i]], 1);
}

// per-1024 chunk sums; +1 per node folds the self loop (cnt zero-initialized)
__global__ void k_scan_bsum(const int* __restrict__ cnt, int n, int* bsum) {
  __shared__ int red[256];
  int b = blockIdx.x, t = threadIdx.x;
  int s = 0;
  for (int i = b * 1024 + t; i < (b + 1) * 1024; i += 256)
    if (i < n) s += cnt[i] + 1;
  red[t] = s;
  __syncthreads();
  for (int o = 128; o > 0; o >>= 1) {
    if (t < o) red[t] += red[t + o];
    __syncthreads();
  }
  if (t == 0) bsum[b] = red[0];
}

__global__ void k_scan_offsets(int* bsum, int nb) {
  if (threadIdx.x == 0 && blockIdx.x == 0) {
    int acc = 0;
    for (int i = 0; i < nb; i++) { int v = bsum[i]; bsum[i] = acc; acc += v; }
  }
}

// scan + self-loop insert fused (nxt aliases cnt); +1 per node folded.
// esrc entries are PRE-SCALED BYTE OFFSETS into xlr (row * 512 elems * 2B = row*1024).
__global__ void k_scan_final(int* __restrict__ cnt, int n,
                             const int* __restrict__ bsum, int* __restrict__ indptr,
                             int* __restrict__ esrc) {
  __shared__ int lds[256];
  int b = blockIdx.x, t = threadIdx.x;
  int base = b * 1024;
  int v[4];
  int s = 0;
#pragma unroll
  for (int j = 0; j < 4; j++) {
    int i = base + t * 4 + j;
    v[j] = (i < n) ? cnt[i] + 1 : 0;
    s += v[j];
  }
  lds[t] = s;
  __syncthreads();
  for (int o = 1; o < 256; o <<= 1) {
    int x = (t >= o) ? lds[t - o] : 0;
    __syncthreads();
    lds[t] += x;
    __syncthreads();
  }
  int run = bsum[b] + lds[t] - s;
#pragma unroll
  for (int j = 0; j < 4; j++) {
    int i = base + t * 4 + j;
    if (i < n) {
      indptr[i] = run;
      esrc[run] = i << 10;   // self loop first (byte offset)
      cnt[i] = run + 1;      // cnt becomes nxt
    } else if (i == n) {
      indptr[n] = run;
    }
    run += v[j];
  }
}

__global__ void k_csr_fill(const int* __restrict__ src, const int* __restrict__ dst,
                           int e, int* nxt, int* esrc) {
  int i = blockIdx.x * blockDim.x + threadIdx.x;
  if (i < e) {
    int p = atomicAdd(&nxt[dst[i]], 1);
    esrc[p] = src[i] << 10;  // byte offset
  }
}

// ---------------- batch segment starts (batch is sorted) ----------------
__global__ void k_batch_starts(const int* __restrict__ batch, int n, int nb, int* starts) {
  int i = blockIdx.x * blockDim.x + threadIdx.x;
  if (i >= n) return;
  int b = batch[i];
  if (i == 0) {
    for (int x = 0; x <= b; x++) starts[x] = 0;
  } else {
    int pb = batch[i - 1];
    if (pb != b)
      for (int x = pb + 1; x <= b; x++) starts[x] = i;
  }
  if (i == n - 1) {
    for (int x = b + 1; x <= nb; x++) starts[x] = n;
  }
}

// ---------------- merged weight prep ----------------
#define SEG_LR (4 * 512 * 64)
#define SEG_F1 (4 * 128 * 64)
#define SEG_F2 (4 * 64 * 128)
#define SEG_N  (4 * 64 * 64)
#define SEG_D  (64 * 64)
#define WPREP_TOTAL (SEG_LR + SEG_F1 + SEG_F2 + 2 * SEG_N + SEG_D)
__global__ void k_wprep_all(const float* __restrict__ Wl, const float* __restrict__ Wr,
                            const float* __restrict__ F1, const float* __restrict__ F2,
                            const float* __restrict__ N1, const float* __restrict__ N2,
                            const float* __restrict__ D1,
                            unsigned short* __restrict__ wLR, unsigned short* __restrict__ wF1,
                            unsigned short* __restrict__ wF2, unsigned short* __restrict__ wN1,
                            unsigned short* __restrict__ wN2, unsigned short* __restrict__ wD1) {
  int idx = blockIdx.x * blockDim.x + threadIdx.x;
  if (idx < SEG_LR) {
    int l = idx / (512 * 64), rem = idx % (512 * 64);
    int c = rem / 64, k = rem % 64;
    float v = (c < 256) ? Wl[(size_t)l * 64 * 256 + k * 256 + c]
                        : Wr[(size_t)l * 64 * 256 + k * 256 + (c - 256)];
    wLR[idx] = f2b(v);
    return;
  }
  idx -= SEG_LR;
  if (idx < SEG_F1) {
    int l = idx / (128 * 64), rem = idx % (128 * 64);
    int c = rem / 64, k = rem % 64;
    wF1[idx] = f2b(F1[(size_t)l * 64 * 128 + k * 128 + c]);
    return;
  }
  idx -= SEG_F1;
  if (idx < SEG_F2) {
    int l = idx / (64 * 128), rem = idx % (64 * 128);
    int c = rem / 128, k = rem % 128;
    wF2[idx] = f2b(F2[(size_t)l * 128 * 64 + k * 64 + c]);
    return;
  }
  idx -= SEG_F2;
  if (idx < SEG_N) {
    int l = idx / (64 * 64), rem = idx % (64 * 64);
    int c = rem / 64, k = rem % 64;
    wN1[idx] = f2b(N1[(size_t)l * 64 * 64 + k * 64 + c]);
    return;
  }
  idx -= SEG_N;
  if (idx < SEG_N) {
    int l = idx / (64 * 64), rem = idx % (64 * 64);
    int c = rem / 64, k = rem % 64;
    wN2[idx] = f2b(N2[(size_t)l * 64 * 64 + k * 64 + c]);
    return;
  }
  idx -= SEG_N;
  if (idx < SEG_D) {
    int c = idx / 64, k = idx % 64;
    wD1[idx] = f2b(D1[k * 64 + c]);
  }
}

// ---------------- encoder (fp32 h only) ----------------
__global__ void k_encoder(const float* __restrict__ x, const float* __restrict__ W,
                          const float* __restrict__ bias, float* __restrict__ h, int n) {
  int idx = blockIdx.x * blockDim.x + threadIdx.x;
  if (idx >= n * 64) return;
  int i = idx >> 6, d = idx & 63;
  float acc = bias[d];
#pragma unroll
  for (int k = 0; k < NIN; k++) acc += x[i * NIN + k] * W[k * 64 + d];
  h[idx] = acc;
}

// ---------------- xlr GEMM: xlr = (h [+ctx]) @ [Wl|Wr], bf16 out, Co=512 ----------------
// grid (GN, 4): block handles 2 of the 8 column-blocks (A packed once per block).
template <bool CTX>
__global__ __launch_bounds__(256) void k_xlr(const float* __restrict__ A,
                                             const float* __restrict__ ctxv,
                                             const int* __restrict__ batch,
                                             const unsigned short* __restrict__ Wt,
                                             unsigned short* __restrict__ Cb, int n) {
  const int lane = threadIdx.x & 63, wave = threadIdx.x >> 6;
  const int row0 = blockIdx.x * 64 + wave * 16;
  const int cb0 = blockIdx.y * 2;
  const int karow = (lane >> 4) * 8;
  const int arow0 = row0 + (lane & 15);
  const int arow = arow0 < n ? arow0 : 0;
  const float* ap = A + (size_t)arow * 64;

  float av[16];
  {
    float4 f0 = *(const float4*)(ap + karow);
    float4 f1 = *(const float4*)(ap + karow + 4);
    float4 f2 = *(const float4*)(ap + 32 + karow);
    float4 f3 = *(const float4*)(ap + 32 + karow + 4);
    av[0] = f0.x; av[1] = f0.y; av[2] = f0.z; av[3] = f0.w;
    av[4] = f1.x; av[5] = f1.y; av[6] = f1.z; av[7] = f1.w;
    av[8] = f2.x; av[9] = f2.y; av[10] = f2.z; av[11] = f2.w;
    av[12] = f3.x; av[13] = f3.y; av[14] = f3.z; av[15] = f3.w;
    if (CTX) {
      const float* cp = ctxv + batch[arow] * 64;
      float4 c0v = *(const float4*)(cp + karow);
      float4 c1v = *(const float4*)(cp + karow + 4);
      float4 c2v = *(const float4*)(cp + 32 + karow);
      float4 c3v = *(const float4*)(cp + 32 + karow + 4);
      av[0] += c0v.x; av[1] += c0v.y; av[2] += c0v.z; av[3] += c0v.w;
      av[4] += c1v.x; av[5] += c1v.y; av[6] += c1v.z; av[7] += c1v.w;
      av[8] += c2v.x; av[9] += c2v.y; av[10] += c2v.z; av[11] += c2v.w;
      av[12] += c3v.x; av[13] += c3v.y; av[14] += c3v.z; av[15] += c3v.w;
    }
  }
  short8v a0 = pack8(av), a1 = pack8(av + 8);

#pragma unroll
  for (int cbi = 0; cbi < 2; cbi++) {
    const int cb = cb0 + cbi;
#pragma unroll
    for (int cc = 0; cc < 4; cc++) {
      const int c = cb * 64 + cc * 16 + (lane & 15);
      f32x4 t = {0.f, 0.f, 0.f, 0.f};
      t = __builtin_amdgcn_mfma_f32_16x16x32_bf16(a0, *(const short8v*)(Wt + (size_t)c * 64 + karow), t, 0, 0, 0);
      t = __builtin_amdgcn_mfma_f32_16x16x32_bf16(a1, *(const short8v*)(Wt + (size_t)c * 64 + 32 + karow), t, 0, 0, 0);
#pragma unroll
      for (int r = 0; r < 4; r++) {
        const int row = row0 + (lane >> 4) * 4 + r;
        if (row < n) Cb[(size_t)row * 512 + c] = f2b(t[r]);
      }
    }
  }
}

// ---------------- fused FFN + n2g + pooling (bf16 residual) ----------------
__global__ __launch_bounds__(256) void k_fnp(const unsigned short* __restrict__ A,   // h2b
                                             const unsigned short* __restrict__ F1t, // [128][64]
                                             const float* __restrict__ fb1,
                                             const unsigned short* __restrict__ F2t, // [64][128]
                                             const float* __restrict__ fb2,
                                             float* __restrict__ hOut,
                                             const unsigned short* __restrict__ N1t, // [64][64]
                                             const float* __restrict__ nb1,
                                             const unsigned short* __restrict__ N2t, // [64][64]
                                             const float* __restrict__ nb2,
                                             const int* __restrict__ batch,
                                             float* __restrict__ psum,
                                             unsigned int* __restrict__ pmax, int n) {
  __shared__ unsigned short tl[4][16 * 136];  // FFN mid (16x128), reused n2g mid (@72)
  __shared__ unsigned short tn[4][16 * 72];   // n2g input (16x64 @72)
  __shared__ float s_sum[64];
  __shared__ unsigned s_max[64];
  const int lane = threadIdx.x & 63, wave = threadIdx.x >> 6;
  const int row0b = blockIdx.x * 64;
  const int row0 = row0b + wave * 16;
  const int karow = (lane >> 4) * 8;
  const int arow = row0 + (lane & 15);
  const size_t abase = (size_t)(arow < n ? arow : 0) * 64 + karow;
  if (threadIdx.x < 64) { s_sum[threadIdx.x] = 0.f; s_max[threadIdx.x] = 0u; }
  short8v a0 = *(const short8v*)(A + abase);
  short8v a1 = *(const short8v*)(A + abase + 32);

  // ---- FFN stage 1: 64 -> 128, leaky, to tl (stride 136) ----
#pragma unroll
  for (int cc = 0; cc < 8; cc++) {
    const int c = cc * 16 + (lane & 15);
    f32x4 t = {0.f, 0.f, 0.f, 0.f};
    t = __builtin_amdgcn_mfma_f32_16x16x32_bf16(a0, *(const short8v*)(F1t + (size_t)c * 64 + karow), t, 0, 0, 0);
    t = __builtin_amdgcn_mfma_f32_16x16x32_bf16(a1, *(const short8v*)(F1t + (size_t)c * 64 + 32 + karow), t, 0, 0, 0);
    const float bv = fb1[c];
#pragma unroll
    for (int r = 0; r < 4; r++) {
      float v = t[r] + bv;
      v = fmaxf(v, 0.2f * v);
      int rr = (lane >> 4) * 4 + r;
      tl[wave][rr * 136 + c] = f2b(v);
    }
  }

  // ---- FFN stage 2: 128 -> 64, +bias +res(bf16 from A) -> h fp32; bf16 to tn ----
  short8v a2[4];
#pragma unroll
  for (int f = 0; f < 4; f++)
    a2[f] = *(const short8v*)(&tl[wave][(lane & 15) * 136 + f * 32 + karow]);

#pragma unroll
  for (int cc = 0; cc < 4; cc++) {
    const int c = cc * 16 + (lane & 15);
    f32x4 t = {0.f, 0.f, 0.f, 0.f};
#pragma unroll
    for (int f = 0; f < 4; f++)
      t = __builtin_amdgcn_mfma_f32_16x16x32_bf16(a2[f], *(const short8v*)(F2t + (size_t)c * 128 + f * 32 + karow), t, 0, 0, 0);
    const float bv = fb2[c];
#pragma unroll
    for (int r = 0; r < 4; r++) {
      const int row = row0 + (lane >> 4) * 4 + r;
      const int rr = (lane >> 4) * 4 + r;
      float v = t[r] + bv + ((row < n) ? b2f(A[(size_t)row * 64 + c]) : 0.f);
      if (row < n) hOut[(size_t)row * 64 + c] = v;
      tn[wave][rr * 72 + c] = f2b(v);
    }
  }

  // ---- n2g stage 1: 64 -> 64, gelu, to tl (@72) ----
  short8v a3[2];
#pragma unroll
  for (int f = 0; f < 2; f++)
    a3[f] = *(const short8v*)(&tn[wave][(lane & 15) * 72 + f * 32 + karow]);

#pragma unroll
  for (int cc = 0; cc < 4; cc++) {
    const int c = cc * 16 + (lane & 15);
    f32x4 t = {0.f, 0.f, 0.f, 0.f};
    t = __builtin_amdgcn_mfma_f32_16x16x32_bf16(a3[0], *(const short8v*)(N1t + (size_t)c * 64 + karow), t, 0, 0, 0);
    t = __builtin_amdgcn_mfma_f32_16x16x32_bf16(a3[1], *(const short8v*)(N1t + (size_t)c * 64 + 32 + karow), t, 0, 0, 0);
    const float bv = nb1[c];
#pragma unroll
    for (int r = 0; r < 4; r++) {
      int rr = (lane >> 4) * 4 + r;
      tl[wave][rr * 72 + c] = f2b(gelu_t(t[r] + bv));
    }
  }

  // ---- n2g stage 2: 64 -> 64 -> pv ----
  short8v a4[2];
#pragma unroll
  for (int f = 0; f < 2; f++)
    a4[f] = *(const short8v*)(&tl[wave][(lane & 15) * 72 + f * 32 + karow]);

  float pv[4][4];
#pragma unroll
  for (int cc = 0; cc < 4; cc++) {
    const int c = cc * 16 + (lane & 15);
    f32x4 t = {0.f, 0.f, 0.f, 0.f};
    t = __builtin_amdgcn_mfma_f32_16x16x32_bf16(a4[0], *(const short8v*)(N2t + (size_t)c * 64 + karow), t, 0, 0, 0);
    t = __builtin_amdgcn_mfma_f32_16x16x32_bf16(a4[1], *(const short8v*)(N2t + (size_t)c * 64 + 32 + karow), t, 0, 0, 0);
    const float bv = nb2[c];
#pragma unroll
    for (int r = 0; r < 4; r++) pv[cc][r] = t[r] + bv;
  }

  // ---- pooling epilogue ----
  __syncthreads();  // s_sum/s_max init visible
  const int blo = batch[row0b];
  const int last = row0b + 63 < n ? row0b + 63 : n - 1;
  const int bhi = batch[last];
  if (blo == bhi && row0b + 63 < n) {
#pragma unroll
    for (int cc = 0; cc < 4; cc++) {
      const int c = cc * 16 + (lane & 15);
      float s = pv[cc][0] + pv[cc][1] + pv[cc][2] + pv[cc][3];
      float mx = fmaxf(fmaxf(pv[cc][0], pv[cc][1]), fmaxf(pv[cc][2], pv[cc][3]));
      atomicAdd(&s_sum[c], s);
      atomicMax(&s_max[c], fkey(mx));
    }
    __syncthreads();
    if (threadIdx.x < 64) {
      atomicAdd(&psum[blo * 64 + threadIdx.x], s_sum[threadIdx.x]);
      atomicMax(&pmax[blo * 64 + threadIdx.x], s_max[threadIdx.x]);
    }
  } else {
#pragma unroll
    for (int cc = 0; cc < 4; cc++) {
      const int c = cc * 16 + (lane & 15);
#pragma unroll
      for (int r = 0; r < 4; r++) {
        const int row = row0 + (lane >> 4) * 4 + r;
        if (row < n) {
          const int b = batch[row];
          atomicAdd(&psum[b * 64 + c], pv[cc][r]);
          atomicMax(&pmax[b * 64 + c], fkey(pv[cc][r]));
        }
      }
    }
  }
}

// ---------------- GATv2 aggregation + residual(+ctx) + LayerNorm (bf16 out only) -------
// esrc entries are byte offsets (row*1024) into xlr.
template <bool CTX>
__global__ __launch_bounds__(256) void k_gat(const unsigned short* __restrict__ xlr,
                                             const float* __restrict__ att,
                                             const float* __restrict__ gbias,
                                             const float* __restrict__ lng,
                                             const float* __restrict__ lnb,
                                             const float* __restrict__ h,
                                             const float* __restrict__ ctxv,
                                             const int* __restrict__ batch,
                                             const int* __restrict__ indptr,
                                             const int* __restrict__ esrc,
                                             unsigned short* __restrict__ h2b, int n) {
  const int wave = threadIdx.x >> 6, lane = threadIdx.x & 63;
  const int node = blockIdx.x * 4 + wave;
  if (node >= n) return;
  const int q = lane >> 4, r = lane & 15;
  const int c = r & 3;
  const int doff = (r >> 2) * 64 + c * 16;
  const char* xbase = (const char*)xlr + 2 * doff;

  float xr_d[16], att_d[16];
  {
    const uint4* xp = (const uint4*)(xlr + (size_t)node * 512 + 256 + doff);
    uint4 u0 = xp[0], u1 = xp[1];
    unpack8(u0, xr_d);
    unpack8(u1, xr_d + 8);
    const float4* ap = (const float4*)(att + doff);
#pragma unroll
    for (int k = 0; k < 4; k++) {
      float4 a = ap[k];
      att_d[4 * k] = a.x; att_d[4 * k + 1] = a.y;
      att_d[4 * k + 2] = a.z; att_d[4 * k + 3] = a.w;
    }
  }

  float acc[16] = {};
  float den = 0.f;
  const int beg = indptr[node], end = indptr[node + 1];

  // 2-deep pipeline: data 1 ahead, esrc (byte offset) 2 ahead
  int j0 = beg + q;
  int s_cur = esrc[(j0 < end) ? j0 : beg];
  const uint4* xp0 = (const uint4*)(xbase + s_cur);
  uint4 u0 = xp0[0], u1 = xp0[1];
  int jn1 = beg + 4 + q;
  int s_nxt = esrc[(jn1 < end && beg + 4 < end) ? jn1 : beg];

  for (int jb = beg; jb < end; jb += 4) {
    const uint4 cu0 = u0, cu1 = u1;
    const bool cvalid = (jb + q) < end;
    if (jb + 4 < end) {
      const uint4* xpn = (const uint4*)(xbase + s_nxt);
      u0 = xpn[0];
      u1 = xpn[1];
      if (jb + 8 < end) {
        const int jn = jb + 8 + q;
        s_nxt = esrc[(jn < end) ? jn : beg];
      }
    }
    float xs[16];
    unpack8(cu0, xs);
    unpack8(cu1, xs + 8);
    float p0 = 0.f, p1 = 0.f, p2 = 0.f, p3 = 0.f;
#pragma unroll
    for (int k = 0; k < 4; k++) {
      float t0 = xs[4 * k + 0] + xr_d[4 * k + 0]; t0 = fmaxf(t0, 0.2f * t0); p0 = fmaf(t0, att_d[4 * k + 0], p0);
      float t1 = xs[4 * k + 1] + xr_d[4 * k + 1]; t1 = fmaxf(t1, 0.2f * t1); p1 = fmaf(t1, att_d[4 * k + 1], p1);
      float t2 = xs[4 * k + 2] + xr_d[4 * k + 2]; t2 = fmaxf(t2, 0.2f * t2); p2 = fmaf(t2, att_d[4 * k + 2], p2);
      float t3 = xs[4 * k + 3] + xr_d[4 * k + 3]; t3 = fmaxf(t3, 0.2f * t3); p3 = fmaf(t3, att_d[4 * k + 3], p3);
    }
    float p = (p0 + p1) + (p2 + p3);
    p += dppf<0xB1>(p);
    p += dppf<0x4E>(p);
    const float pw = cvalid ? __expf(fminf(p, 60.f)) : 0.f;
    den += pw;
#pragma unroll
    for (int d = 0; d < 16; d++) acc[d] = fmaf(pw, xs[d], acc[d]);
  }

  den += __shfl_xor(den, 16, 64);
  den += __shfl_xor(den, 32, 64);
#pragma unroll
  for (int d = 0; d < 16; d++) {
    acc[d] += __shfl_xor(acc[d], 16, 64);
    acc[d] += __shfl_xor(acc[d], 32, 64);
  }

  const float rden = 0.25f / (den + 1e-16f);
  float y[16];
  float s4 = 0.f;
  const float4* hp = (const float4*)(h + (size_t)node * 64 + c * 16);
  const float4* gp = (const float4*)(gbias + c * 16);
  const float4* cp = CTX ? (const float4*)(ctxv + batch[node] * 64 + c * 16) : nullptr;
#pragma unroll
  for (int k = 0; k < 4; k++) {
    float4 hv = hp[k], gv = gp[k];
    if (CTX) {
      float4 cv = cp[k];
      hv.x += cv.x; hv.y += cv.y; hv.z += cv.z; hv.w += cv.w;
    }
    float hf[4] = {hv.x, hv.y, hv.z, hv.w};
    float gf[4] = {gv.x, gv.y, gv.z, gv.w};
#pragma unroll
    for (int d2 = 0; d2 < 4; d2++) {
      int d = 4 * k + d2;
      float v = acc[d] * rden;
      v += dppf<0x124>(v);
      v += dppf<0x128>(v);
      y[d] = hf[d2] + v + gf[d2];
      s4 += y[d];
    }
  }

  const float mu = wave_sum(s4) * (1.f / 1024.f);
  float v4 = 0.f;
  float dv[16];
#pragma unroll
  for (int d = 0; d < 16; d++) {
    dv[d] = y[d] - mu;
    v4 += dv[d] * dv[d];
  }
  const float var = wave_sum(v4) * (1.f / 1024.f);
  const float rstd = rsqrtf(var + 1e-5f);

  if (lane < 4) {
    uint2* outb = (uint2*)(h2b + (size_t)node * 64 + lane * 16);
    const float4* lgp = (const float4*)(lng + lane * 16);
    const float4* lbp = (const float4*)(lnb + lane * 16);
#pragma unroll
    for (int k = 0; k < 4; k++) {
      float4 g = lgp[k], b = lbp[k];
      float o0 = dv[4 * k + 0] * rstd * g.x + b.x;
      float o1 = dv[4 * k + 1] * rstd * g.y + b.y;
      float o2 = dv[4 * k + 2] * rstd * g.z + b.z;
      float o3 = dv[4 * k + 3] * rstd * g.w + b.w;
      uint2 pk;
      pk.x = (unsigned int)f2b(o0) | ((unsigned int)f2b(o1) << 16);
      pk.y = (unsigned int)f2b(o2) | ((unsigned int)f2b(o3) << 16);
      outb[k] = pk;
    }
  }
}

// ---------------- ctx MLP from pooled psum/pmax ----------------
__global__ void k_ctx2(const float* __restrict__ psum, const unsigned int* __restrict__ pmax,
                       const int* __restrict__ starts,
                       const float* __restrict__ W1, const float* __restrict__ b1,
                       const float* __restrict__ W2, const float* __restrict__ b2,
                       float* __restrict__ ctx) {
  int b = blockIdx.x;
  int t = threadIdx.x;  // 128 threads
  __shared__ float g[128], tt[64];
  int cnt = starts[b + 1] - starts[b];
  if (t < 64) {
    g[t] = psum[b * 64 + t] / fmaxf((float)cnt, 1.0f);
  } else {
    g[t] = fkey_inv(pmax[b * 64 + (t - 64)]);
  }
  __syncthreads();
  if (t < 64) {
    float acc = b1[t];
    for (int k = 0; k < 128; k++) acc += g[k] * W1[k * 64 + t];
    tt[t] = gelu_t(acc);
  }
  __syncthreads();
  if (t < 64) {
    float acc2 = b2[t];
    for (int k = 0; k < 64; k++) acc2 += tt[k] * W2[k * 64 + t];
    ctx[b * 64 + t] = acc2;
  }
}

// ---------------- fused decoder: out = gelu((h+ctx)@W1+b1)@W2 + b2 ----------------
__global__ __launch_bounds__(256) void k_dec(const float* __restrict__ A,            // h fp32
                                             const float* __restrict__ ctxv,
                                             const int* __restrict__ batch,
                                             const unsigned short* __restrict__ W1t,
                                             const float* __restrict__ b1,
                                             const float* __restrict__ W2,
                                             const float* __restrict__ b2,
                                             float* __restrict__ out, int n) {
  const int lane = threadIdx.x & 63, wave = threadIdx.x >> 6;
  const int row0 = blockIdx.x * 64 + wave * 16;
  const int karow = (lane >> 4) * 8;
  const int arow0 = row0 + (lane & 15);
  const int arow = arow0 < n ? arow0 : 0;
  const float* ap = A + (size_t)arow * 64;
  const float* cp = ctxv + batch[arow] * 64;

  float av[16];
  {
    float4 f0 = *(const float4*)(ap + karow);
    float4 f1 = *(const float4*)(ap + karow + 4);
    float4 f2 = *(const float4*)(ap + 32 + karow);
    float4 f3 = *(const float4*)(ap + 32 + karow + 4);
    float4 c0v = *(const float4*)(cp + karow);
    float4 c1v = *(const float4*)(cp + karow + 4);
    float4 c2v = *(const float4*)(cp + 32 + karow);
    float4 c3v = *(const float4*)(cp + 32 + karow + 4);
    av[0] = f0.x + c0v.x; av[1] = f0.y + c0v.y; av[2] = f0.z + c0v.z; av[3] = f0.w + c0v.w;
    av[4] = f1.x + c1v.x; av[5] = f1.y + c1v.y; av[6] = f1.z + c1v.z; av[7] = f1.w + c1v.w;
    av[8] = f2.x + c2v.x; av[9] = f2.y + c2v.y; av[10] = f2.z + c2v.z; av[11] = f2.w + c2v.w;
    av[12] = f3.x + c3v.x; av[13] = f3.y + c3v.y; av[14] = f3.z + c3v.z; av[15] = f3.w + c3v.w;
  }
  short8v a0 = pack8(av), a1 = pack8(av + 8);

  float o0[4] = {}, o1[4] = {};
#pragma unroll
  for (int cc = 0; cc < 4; cc++) {
    const int cidx = cc * 16 + (lane & 15);
    f32x4 t = {0.f, 0.f, 0.f, 0.f};
    t = __builtin_amdgcn_mfma_f32_16x16x32_bf16(a0, *(const short8v*)(W1t + (size_t)cidx * 64 + karow), t, 0, 0, 0);
    t = __builtin_amdgcn_mfma_f32_16x16x32_bf16(a1, *(const short8v*)(W1t + (size_t)cidx * 64 + 32 + karow), t, 0, 0, 0);
    const float bv = b1[cidx];
    const float w0 = W2[cidx * 2 + 0], w1 = W2[cidx * 2 + 1];
#pragma unroll
    for (int r = 0; r < 4; r++) {
      float v = gelu_t(t[r] + bv);
      o0[r] = fmaf(v, w0, o0[r]);
      o1[r] = fmaf(v, w1, o1[r]);
    }
  }
#pragma unroll
  for (int m = 1; m < 16; m <<= 1) {
#pragma unroll
    for (int r = 0; r < 4; r++) {
      o0[r] += __shfl_xor(o0[r], m, 64);
      o1[r] += __shfl_xor(o1[r], m, 64);
    }
  }
  if ((lane & 15) == 0) {
#pragma unroll
    for (int r = 0; r < 4; r++) {
      const int row = row0 + (lane >> 4) * 4 + r;
      if (row < n) {
        out[2 * row] = o0[r] + b2[0];
        out[2 * row + 1] = o1[r] + b2[1];
      }
    }
  }
}

// ---------------- host ----------------
extern "C" void kernel_launch(void* const* d_in, const int* in_sizes, int n_in,
                              void* d_out, int out_size, void* d_ws, size_t ws_size,
                              hipStream_t stream) {
  const float* x = (const float*)d_in[0];
  const int* ei = (const int*)d_in[1];
  const int* batch = (const int*)d_in[2];
  const float* enc_W = (const float*)d_in[3];
  const float* enc_b = (const float*)d_in[4];
  const float* gat_Wl = (const float*)d_in[5];
  const float* gat_Wr = (const float*)d_in[6];
  const float* gat_att = (const float*)d_in[7];
  const float* gat_b = (const float*)d_in[8];
  const float* ln_g = (const float*)d_in[9];
  const float* ln_b = (const float*)d_in[10];
  const float* ffn_W1 = (const float*)d_in[11];
  const float* ffn_b1 = (const float*)d_in[12];
  const float* ffn_W2 = (const float*)d_in[13];
  const float* ffn_b2 = (const float*)d_in[14];
  const float* n2g_W1 = (const float*)d_in[15];
  const float* n2g_b1 = (const float*)d_in[16];
  const float* n2g_W2 = (const float*)d_in[17];
  const float* n2g_b2 = (const float*)d_in[18];
  const float* g2n_W1 = (const float*)d_in[19];
  const float* g2n_b1 = (const float*)d_in[20];
  const float* g2n_W2 = (const float*)d_in[21];
  const float* g2n_b2 = (const float*)d_in[22];
  const float* dec_W1 = (const float*)d_in[23];
  const float* dec_b1 = (const float*)d_in[24];
  const float* dec_W2 = (const float*)d_in[25];
  const float* dec_b2 = (const float*)d_in[26];

  const int N = NN, E = EE;
  const int* e_src = ei;
  const int* e_dst = ei + E;

  // ---- workspace carve ----
  // [psum_all | pmax_all | cnt] contiguous -> one upfront memset.
  float* h = (float*)d_ws;                    // N*64
  float* ctx = h + (size_t)N * 64;            // B*64
  float* psum_all = ctx + BBATCH * 64;        // 4 * B*64
  unsigned int* pmax_all = (unsigned int*)(psum_all + 4 * BBATCH * 64);  // 4 * B*64
  int* cnt = (int*)(pmax_all + 4 * BBATCH * 64);  // N (zero-init; becomes nxt)
  int* indptr = cnt + N;                      // N+1
  int* esrc = indptr + N + 1;                 // E+N
  int* bsum = esrc + (E + N);                 // 64
  int* starts = bsum + 64;                    // B+1
  size_t off = (size_t)(starts + BBATCH + 1) - (size_t)d_ws;
  off = (off + 15) & ~(size_t)15;
  unsigned short* h2b = (unsigned short*)((char*)d_ws + off);  // N*64
  unsigned short* xlr = h2b + (size_t)N * 64;                  // N*512 (xl | xr)
  unsigned short* wLR = xlr + (size_t)N * 512;                 // 4*512*64
  unsigned short* wF1 = wLR + SEG_LR;
  unsigned short* wF2 = wF1 + SEG_F1;
  unsigned short* wN1 = wF2 + SEG_F2;
  unsigned short* wN2 = wN1 + SEG_N;
  unsigned short* wD1 = wN2 + SEG_N;

  const int TPB = 256;
  const int NBLK_SCAN = (N + 1 + 1023) / 1024;

  // ---- zero psum/pmax/cnt in one memset ----
  hipMemsetAsync(psum_all, 0,
                 (size_t)4 * BBATCH * 64 * (sizeof(float) + sizeof(unsigned int)) +
                 (size_t)N * sizeof(int),
                 stream);

  // ---- weight prep (one dispatch) ----
  hipLaunchKernelGGL(k_wprep_all, dim3((WPREP_TOTAL + 255) / 256), dim3(256), 0, stream,
                     gat_Wl, gat_Wr, ffn_W1, ffn_W2, n2g_W1, n2g_W2, dec_W1,
                     wLR, wF1, wF2, wN1, wN2, wD1);

  // ---- CSR build (self-loop +1 folded into scans; esrc = byte offsets) ----
  hipLaunchKernelGGL(k_count_edges, dim3((E + TPB - 1) / TPB), dim3(TPB), 0, stream, e_dst, E, cnt);
  hipLaunchKernelGGL(k_scan_bsum, dim3(NBLK_SCAN), dim3(256), 0, stream, cnt, N, bsum);
  hipLaunchKernelGGL(k_scan_offsets, dim3(1), dim3(64), 0, stream, bsum, NBLK_SCAN);
  hipLaunchKernelGGL(k_scan_final, dim3(NBLK_SCAN), dim3(256), 0, stream, cnt, N, bsum, indptr, esrc);
  hipLaunchKernelGGL(k_csr_fill, dim3((E + TPB - 1) / TPB), dim3(TPB), 0, stream, e_src, e_dst, E, cnt, esrc);
  hipLaunchKernelGGL(k_batch_starts, dim3((N + TPB - 1) / TPB), dim3(TPB), 0, stream, batch, N, BBATCH, starts);

  // ---- encoder ----
  hipLaunchKernelGGL(k_encoder, dim3((N * 64 + TPB - 1) / TPB), dim3(TPB), 0, stream,
                     x, enc_W, enc_b, h, N);

  const int GN = (N + 63) / 64;  // 782

  for (int l = 0; l < NLAYER; l++) {
    const unsigned short* LRt = wLR + (size_t)l * 512 * 64;
    const unsigned short* F1t = wF1 + (size_t)l * 128 * 64;
    const unsigned short* F2t = wF2 + (size_t)l * 64 * 128;
    const unsigned short* N1t = wN1 + (size_t)l * 64 * 64;
    const unsigned short* N2t = wN2 + (size_t)l * 64 * 64;
    const float* attl = gat_att + (size_t)l * 256;
    const float* gbl = gat_b + (size_t)l * 64;
    const float* lngl = ln_g + (size_t)l * 64;
    const float* lnbl = ln_b + (size_t)l * 64;
    const float* fb1 = ffn_b1 + (size_t)l * 128;
    const float* fb2 = ffn_b2 + (size_t)l * 64;
    const float* nb1 = n2g_b1 + (size_t)l * 64;
    const float* nb2 = n2g_b2 + (size_t)l * 64;
    const float* gW1 = g2n_W1 + (size_t)l * 128 * 64;
    const float* gb1 = g2n_b1 + (size_t)l * 64;
    const float* gW2 = g2n_W2 + (size_t)l * 64 * 64;
    const float* gb2 = g2n_b2 + (size_t)l * 64;
    float* psumL = psum_all + (size_t)l * BBATCH * 64;
    unsigned int* pmaxL = pmax_all + (size_t)l * BBATCH * 64;

    // xlr = (h [+ctx_{l-1}]) @ [Wl|Wr]  — grid (GN,4), 2 col-blocks per block
    if (l == 0)
      hipLaunchKernelGGL((k_xlr<false>), dim3(GN, 4), dim3(256), 0, stream,
                         h, nullptr, nullptr, LRt, xlr, N);
    else
      hipLaunchKernelGGL((k_xlr<true>), dim3(GN, 4), dim3(256), 0, stream,
                         h, ctx, batch, LRt, xlr, N);
    // GAT aggregate + residual(+ctx) + LN -> h2b (bf16 only)
    if (l == 0)
      hipLaunchKernelGGL((k_gat<false>), dim3((N + 3) / 4), dim3(256), 0, stream,
                         xlr, attl, gbl, lngl, lnbl, h, nullptr, nullptr, indptr, esrc, h2b, N);
    else
      hipLaunchKernelGGL((k_gat<true>), dim3((N + 3) / 4), dim3(256), 0, stream,
                         xlr, attl, gbl, lngl, lnbl, h, ctx, batch, indptr, esrc, h2b, N);
    // fused FFN + n2g + pooling -> h, psum/pmax
    hipLaunchKernelGGL(k_fnp, dim3(GN), dim3(256), 0, stream,
                       h2b, F1t, fb1, F2t, fb2, h,
                       N1t, nb1, N2t, nb2, batch, psumL, pmaxL, N);
    // ctx MLP
    hipLaunchKernelGGL(k_ctx2, dim3(BBATCH), dim3(128), 0, stream,
                       psumL, pmaxL, starts, gW1, gb1, gW2, gb2, ctx);
  }

  // fused decoder (adds final ctx)
  hipLaunchKernelGGL(k_dec, dim3(GN), dim3(256), 0, stream,
                     h, ctx, batch, wD1, dec_b1, dec_W2, dec_b2, (float*)d_out, N);
}